// Round 1
// baseline (776.346 us; speedup 1.0000x reference)
//
#include <hip/hip_runtime.h>

#define NN 50000
#define NE 500000
#define DD 128
#define NL 4
#define NG 64
#define FIXED_DIM 10000
#define BN_EPS 1e-5f
#define NB 196   // ceil(NN/256)

typedef unsigned short u16;
typedef unsigned int u32;
typedef __attribute__((ext_vector_type(8))) short bf16x8;
typedef __attribute__((ext_vector_type(4))) float f32x4;

__device__ __forceinline__ float bf2f(u16 u) {
    return __uint_as_float(((u32)u) << 16);
}
__device__ __forceinline__ u16 f2bf(float f) {
    u32 u = __float_as_uint(f);
    return (u16)((u + 0x7FFFu + ((u >> 16) & 1u)) >> 16);
}
// adaptive float-INPUT load (isbf: bf16 vs fp32)
__device__ __forceinline__ float ldf(const void* p, size_t i, int isbf) {
    return isbf ? bf2f(((const u16*)p)[i]) : ((const float*)p)[i];
}

// fused preamble: block 0 = dtype probe; block 1 = goff binary search;
// blocks 2+ = zero of [stats .. sem] region (no cross-block deps).
__global__ void k_pre(const void* __restrict__ vb, int* __restrict__ flag,
                      const int* __restrict__ batch, int* __restrict__ goff,
                      float* __restrict__ zbase, int zwords) {
    int b = blockIdx.x, t = threadIdx.x;
    if (b == 0) {
        __shared__ int ok[256];
        float v = (t < 128) ? bf2f(((const u16*)vb)[t]) : 0.f;
        ok[t] = (t < 128) ? ((fabsf(v) < 1000.f) ? 1 : 0) : 1;
        __syncthreads();
        for (int off = 128; off; off >>= 1) {
            if (t < off) ok[t] &= ok[t + off];
            __syncthreads();
        }
        if (t == 0) *flag = ok[0];
    } else if (b == 1) {
        if (t <= NG) {
            int lo = 0, hi = NN;
            while (lo < hi) {
                int mid = (lo + hi) >> 1;
                if (batch[mid] < t) lo = mid + 1; else hi = mid;
            }
            goff[t] = lo;
        }
    } else {
        int i = (b - 2) * 256 + t;
        if (i < zwords) zbase[i] = 0.f;
    }
}

// merged: blocks 0..11 convert 6 per-layer param tensors (6*NL*DD = 3072)
// to fp32; blocks 12.. pre-swizzle 8 weight matrices into MFMA B-frag order:
// Wsw[m*16384 + ((nt*4+ks)*64 + lane)*8 + j]
//   = W_m[ks*32 + (lane>>4)*8 + j][nt*16 + (lane&15)]   (bf16)
__global__ void k_cvtswz(const void* b1, const void* b2, const void* g1,
                         const void* be1, const void* g2, const void* be2,
                         const void* __restrict__ w1, const void* __restrict__ w2,
                         float* __restrict__ pc, u16* __restrict__ Wsw,
                         const int* __restrict__ flag) {
    int b = blockIdx.x, tt = threadIdx.x;
    if (b < 12) {
        int t = b * 256 + tt;            // < 3072 exactly
        int p = t >> 9, j = t & 511;
        const void* s = (p == 0) ? b1 : (p == 1) ? b2 : (p == 2) ? g1
                      : (p == 3) ? be1 : (p == 4) ? g2 : be2;
        pc[t] = ldf(s, j, *flag);
    } else {
        int t = (b - 12) * 256 + tt;     // < 131072 exactly
        int m    = t >> 14;
        int idx  = t & 16383;
        int nt   = idx >> 11;
        int ks   = (idx >> 9) & 3;
        int lane = (idx >> 3) & 63;
        int j    = idx & 7;
        int row = ks * 32 + (lane >> 4) * 8 + j;
        int col = nt * 16 + (lane & 15);
        const void* src = (m < 4) ? w1 : w2;
        size_t off = (size_t)(m & 3) * DD * DD + (size_t)row * DD + col;
        Wsw[t] = f2bf(ldf(src, off, *flag));
    }
}

__global__ void k_deg(const int* __restrict__ dst, int* __restrict__ deg) {
    int i = blockIdx.x * 256 + threadIdx.x;
    if (i < NE) atomicAdd(&deg[dst[i]], 1);
}

// scan stage 1 + (last-block) stage 2: per-block sums -> exclusive scan of bsum.
// Device-scope atomics for cross-XCD visibility within the kernel.
__global__ void k_scan12(const int* __restrict__ deg, int* __restrict__ bsum,
                         int* __restrict__ sem) {
    __shared__ int S[256];
    __shared__ int lastB;
    int b = blockIdx.x, t = threadIdx.x;
    int i = b * 256 + t;
    S[t] = (i < NN) ? deg[i] : 0;
    __syncthreads();
    for (int off = 128; off; off >>= 1) {
        if (t < off) S[t] += S[t + off];
        __syncthreads();
    }
    if (t == 0) {
        atomicExch(&bsum[b], S[0]);
        __threadfence();
        lastB = (atomicAdd(&sem[0], 1) == gridDim.x - 1);
    }
    __syncthreads();
    if (!lastB) return;
    __threadfence();
    int v = (t < NB) ? atomicAdd(&bsum[t], 0) : 0;
    S[t] = v;
    __syncthreads();
    for (int off = 1; off < 256; off <<= 1) {
        int x = (t >= off) ? S[t - off] : 0;
        __syncthreads();
        S[t] += x;
        __syncthreads();
    }
    if (t < NB) bsum[t] = S[t] - v;                 // exclusive
}

// merged: blocks 0..NB-1 finish the rowptr scan; blocks NB.. compute
// h0 = vw[feat] + vb + deg_emb[min(deg,1000)] -> B (bf16).
__global__ void k_scan3init(const int* __restrict__ deg, const int* __restrict__ bsum,
                            int* __restrict__ rowptr,
                            const int* __restrict__ feat, const void* __restrict__ vw,
                            const void* __restrict__ vb, const void* __restrict__ demb,
                            u16* __restrict__ B, const int* __restrict__ flag) {
    __shared__ int S[256];
    int b = blockIdx.x, t = threadIdx.x;
    if (b < NB) {
        int i = b * 256 + t;
        int v = (i < NN) ? deg[i] : 0;
        S[t] = v;
        __syncthreads();
        for (int off = 1; off < 256; off <<= 1) {
            int x = (t >= off) ? S[t - off] : 0;
            __syncthreads();
            S[t] += x;
            __syncthreads();
        }
        if (i < NN) rowptr[i] = bsum[b] + S[t] - v;
        if (i == NN - 1) rowptr[NN] = bsum[b] + S[t];   // == NE
    } else {
        int idx = (b - NB) * 256 + t;
        if (idx >= NN * DD) return;
        int n = idx >> 7, c = idx & 127;
        int isbf = *flag;
        int f = feat[n] % FIXED_DIM;
        int dg = min(deg[n], 1000);
        B[idx] = f2bf(ldf(vw, (size_t)f * DD + c, isbf)
                    + ldf(vb, c, isbf)
                    + ldf(demb, (size_t)dg * DD + c, isbf));
    }
}

__global__ void k_fill(const int* __restrict__ src, const int* __restrict__ dst,
                       const int* __restrict__ rowptr, int* __restrict__ cursor,
                       int* __restrict__ colidx) {
    int e = blockIdx.x * 256 + threadIdx.x;
    if (e >= NE) return;
    int d = dst[e];
    int p = atomicAdd(&cursor[d], 1);
    colidx[rowptr[d] + p] = src[e];
}

// ---- fused GIN aggregation + GEMM1 (z1 = Agg @ W1 + b1), 64 rows/block ----
// Gather phase: wave w aggregates rows w*16..w*16+15 (lane = 2 cols), applying
//   f(x) = AFF ? relu(a*x+b) : x  (a,b from prev layer's BN2 stats),
//   Agg[n] = f(B[n]) + sum_{j in row n} f(B[colidx[j]]),
// writing bf16 directly into the At LDS tile (identical rounding to the old
// Agg16 path). MFMA phase: wave w owns one 16-row M-tile; 32 MFMAs/wave.
// LDS: Wl 32K + At 17.4K = 50.4 KB -> 3 blocks/CU (12 waves/CU for gather MLP).
// Epilogue writes fp32 z1 + per-column sum/sumsq atomics (BN1 stats).
template <bool AFF>
__global__ __launch_bounds__(256, 3) void k_ag1(
        const u16* __restrict__ Bv, const int* __restrict__ rowptr,
        const int* __restrict__ colidx, const u16* __restrict__ Wsw,
        const float* __restrict__ bias,
        const float* __restrict__ gIn, const float* __restrict__ bIn,
        const float* __restrict__ sIn, const float* __restrict__ qIn,
        float* __restrict__ Out, float* __restrict__ ssum, float* __restrict__ ssq) {
    __shared__ u16 Wl[16384];          // 32 KB swizzled W1
    __shared__ u16 At[64 * 136];       // 17.4 KB bf16 A-tile, pitch 136
    float* RedS = (float*)At;          // alias At after MFMA loop
    float* RedQ = RedS + 512;
    const int t = threadIdx.x;
    const int w = t >> 6;
    const int ln = t & 63;
    const int row0 = blockIdx.x * 64;

    // stage swizzled W: 2048 uint4 blockwide
    {
        const uint4* s = (const uint4*)Wsw;
        uint4* d = (uint4*)Wl;
        #pragma unroll
        for (int i = 0; i < 8; i++) d[t + i * 256] = s[t + i * 256];
    }

    // gather phase: aggregation straight into At
    {
        const int c = ln * 2;
        float a0 = 1.f, b0 = 0.f, a1 = 1.f, b1 = 0.f;
        if (AFF) {
            float inv = 1.0f / (float)NN;
            float mu0 = sIn[c] * inv, mu1 = sIn[c + 1] * inv;
            float v0 = fmaxf(qIn[c] * inv - mu0 * mu0, 0.f);
            float v1 = fmaxf(qIn[c + 1] * inv - mu1 * mu1, 0.f);
            a0 = gIn[c] * rsqrtf(v0 + BN_EPS);
            a1 = gIn[c + 1] * rsqrtf(v1 + BN_EPS);
            b0 = bIn[c] - a0 * mu0;
            b1 = bIn[c + 1] - a1 * mu1;
        }
        for (int rr = 0; rr < 16; rr++) {
            int lr = w * 16 + rr;
            int gr = row0 + lr;
            float s0 = 0.f, s1 = 0.f;
            if (gr < NN) {
                u32 wd = *(const u32*)&Bv[(size_t)gr * DD + c];
                float x0 = bf2f((u16)(wd & 0xFFFF)), x1 = bf2f((u16)(wd >> 16));
                s0 = AFF ? fmaxf(fmaf(a0, x0, b0), 0.f) : x0;
                s1 = AFF ? fmaxf(fmaf(a1, x1, b1), 0.f) : x1;
                int lo = rowptr[gr], hi = rowptr[gr + 1];
                int j = lo;
                for (; j + 4 <= hi; j += 4) {
                    int m0 = colidx[j], m1 = colidx[j + 1];
                    int m2 = colidx[j + 2], m3 = colidx[j + 3];
                    u32 wd0 = *(const u32*)&Bv[(size_t)m0 * DD + c];
                    u32 wd1 = *(const u32*)&Bv[(size_t)m1 * DD + c];
                    u32 wd2 = *(const u32*)&Bv[(size_t)m2 * DD + c];
                    u32 wd3 = *(const u32*)&Bv[(size_t)m3 * DD + c];
                    float y;
                    y = bf2f((u16)(wd0 & 0xFFFF)); s0 += AFF ? fmaxf(fmaf(a0, y, b0), 0.f) : y;
                    y = bf2f((u16)(wd0 >> 16));    s1 += AFF ? fmaxf(fmaf(a1, y, b1), 0.f) : y;
                    y = bf2f((u16)(wd1 & 0xFFFF)); s0 += AFF ? fmaxf(fmaf(a0, y, b0), 0.f) : y;
                    y = bf2f((u16)(wd1 >> 16));    s1 += AFF ? fmaxf(fmaf(a1, y, b1), 0.f) : y;
                    y = bf2f((u16)(wd2 & 0xFFFF)); s0 += AFF ? fmaxf(fmaf(a0, y, b0), 0.f) : y;
                    y = bf2f((u16)(wd2 >> 16));    s1 += AFF ? fmaxf(fmaf(a1, y, b1), 0.f) : y;
                    y = bf2f((u16)(wd3 & 0xFFFF)); s0 += AFF ? fmaxf(fmaf(a0, y, b0), 0.f) : y;
                    y = bf2f((u16)(wd3 >> 16));    s1 += AFF ? fmaxf(fmaf(a1, y, b1), 0.f) : y;
                }
                for (; j < hi; j++) {
                    int m = colidx[j];
                    u32 wd2 = *(const u32*)&Bv[(size_t)m * DD + c];
                    float y0 = bf2f((u16)(wd2 & 0xFFFF)), y1 = bf2f((u16)(wd2 >> 16));
                    s0 += AFF ? fmaxf(fmaf(a0, y0, b0), 0.f) : y0;
                    s1 += AFF ? fmaxf(fmaf(a1, y1, b1), 0.f) : y1;
                }
            }
            *(u32*)&At[lr * 136 + c] = ((u32)f2bf(s1) << 16) | (u32)f2bf(s0);
        }
    }
    __syncthreads();

    const int quad = ln >> 4;
    const int lq   = ln & 15;

    f32x4 acc[8];
    #pragma unroll
    for (int nt = 0; nt < 8; nt++) acc[nt] = (f32x4){0.f, 0.f, 0.f, 0.f};

    const u16* aRow = &At[(w * 16 + lq) * 136 + quad * 8];
    #pragma unroll
    for (int ks = 0; ks < 4; ks++) {
        bf16x8 a = *(const bf16x8*)&aRow[ks * 32];
        #pragma unroll
        for (int nt = 0; nt < 8; nt++) {
            bf16x8 b = *(const bf16x8*)&Wl[((nt * 4 + ks) * 64 + ln) * 8];
            acc[nt] = __builtin_amdgcn_mfma_f32_16x16x32_bf16(a, b, acc[nt], 0, 0, 0);
        }
    }
    __syncthreads();   // At dead; RedS/RedQ alias it

    const int rb = row0 + w * 16 + quad * 4;
    #pragma unroll
    for (int nt = 0; nt < 8; nt++) {
        int col = nt * 16 + lq;
        float bv = bias[col];
        float s = 0.f, q = 0.f;
        #pragma unroll
        for (int r = 0; r < 4; r++) {
            int gr = rb + r;
            if (gr < NN) {
                float val = acc[nt][r] + bv;
                Out[(size_t)gr * DD + col] = val;
                s += val; q += val * val;
            }
        }
        s += __shfl_xor(s, 16); q += __shfl_xor(q, 16);
        s += __shfl_xor(s, 32); q += __shfl_xor(q, 32);
        if (quad == 0) { RedS[w * 128 + col] = s; RedQ[w * 128 + col] = q; }
    }
    __syncthreads();
    if (t < 128) {
        float s = RedS[t] + RedS[128 + t] + RedS[256 + t] + RedS[384 + t];
        float q = RedQ[t] + RedQ[128 + t] + RedQ[256 + t] + RedQ[384 + t];
        atomicAdd(&ssum[t], s);
        atomicAdd(&ssq[t], q);
    }
}

// ---- MFMA GEMM2, 128 rows x 128 cols per block (unchanged from baseline) ----
// Out = f(In) @ W + bias; f = AFF ? relu(aff*x+b) : id.
template <bool IN16, bool OUT16, bool AFF>
__global__ __launch_bounds__(256, 2) void k_gemm(
        const void* In, const u16* __restrict__ Wsw,
        const float* __restrict__ bias,
        const float* __restrict__ gIn, const float* __restrict__ bIn,
        const float* __restrict__ sIn, const float* __restrict__ qIn,
        void* Out, float* __restrict__ ssum, float* __restrict__ ssq,
        int nRows) {
    __shared__ u16 Wl[16384];          // 32 KB swizzled W
    __shared__ u16 At[128 * 136];      // 34.8 KB bf16 A-tile, pitch 136
    __shared__ float affS[256];        // 1 KB
    float* RedS = (float*)At;          // alias At after MFMA loop
    float* RedQ = RedS + 512;
    const int t = threadIdx.x;
    const int row0 = blockIdx.x * 128;

    if (AFF) {
        if (t < 128) {
            float inv = 1.0f / (float)NN;
            float mu = sIn[t] * inv;
            float var = fmaxf(qIn[t] * inv - mu * mu, 0.f);
            float a = gIn[t] * rsqrtf(var + BN_EPS);
            affS[t] = a;
            affS[128 + t] = bIn[t] - a * mu;
        }
        __syncthreads();
    }

    {
        const uint4* s = (const uint4*)Wsw;
        uint4* d = (uint4*)Wl;
        #pragma unroll
        for (int i = 0; i < 8; i++) d[t + i * 256] = s[t + i * 256];
    }
    if (IN16) {
        for (int i = t; i < 2048; i += 256) {
            int r  = i >> 4;
            int c8 = (i & 15) * 8;
            int gr = row0 + r;
            uint4 v = make_uint4(0u, 0u, 0u, 0u);
            if (gr < nRows) v = *(const uint4*)&((const u16*)In)[(size_t)gr * DD + c8];
            *(uint4*)&At[r * 136 + c8] = v;
        }
    } else {
        for (int i = t; i < 4096; i += 256) {
            int r  = i >> 5;
            int c4 = (i & 31) * 4;
            int gr = row0 + r;
            float4 v = make_float4(0.f, 0.f, 0.f, 0.f);
            if (gr < nRows) {
                v = *(const float4*)&((const float*)In)[(size_t)gr * DD + c4];
                if (AFF) {
                    v.x = fmaxf(fmaf(affS[c4 + 0], v.x, affS[128 + c4 + 0]), 0.f);
                    v.y = fmaxf(fmaf(affS[c4 + 1], v.y, affS[128 + c4 + 1]), 0.f);
                    v.z = fmaxf(fmaf(affS[c4 + 2], v.z, affS[128 + c4 + 2]), 0.f);
                    v.w = fmaxf(fmaf(affS[c4 + 3], v.w, affS[128 + c4 + 3]), 0.f);
                }
            }
            ushort4 o;
            o.x = f2bf(v.x); o.y = f2bf(v.y); o.z = f2bf(v.z); o.w = f2bf(v.w);
            *(ushort4*)&At[r * 136 + c4] = o;
        }
    }
    __syncthreads();

    const int w    = t >> 6;
    const int ln   = t & 63;
    const int quad = ln >> 4;
    const int lq   = ln & 15;

    f32x4 acc0[8], acc1[8];
    #pragma unroll
    for (int nt = 0; nt < 8; nt++) {
        acc0[nt] = (f32x4){0.f, 0.f, 0.f, 0.f};
        acc1[nt] = (f32x4){0.f, 0.f, 0.f, 0.f};
    }

    const u16* aRow0 = &At[(w * 32 + lq) * 136 + quad * 8];
    const u16* aRow1 = &At[(w * 32 + 16 + lq) * 136 + quad * 8];
    #pragma unroll
    for (int ks = 0; ks < 4; ks++) {
        bf16x8 a0 = *(const bf16x8*)&aRow0[ks * 32];
        bf16x8 a1 = *(const bf16x8*)&aRow1[ks * 32];
        #pragma unroll
        for (int nt = 0; nt < 8; nt++) {
            bf16x8 b = *(const bf16x8*)&Wl[((nt * 4 + ks) * 64 + ln) * 8];
            acc0[nt] = __builtin_amdgcn_mfma_f32_16x16x32_bf16(a0, b, acc0[nt], 0, 0, 0);
            acc1[nt] = __builtin_amdgcn_mfma_f32_16x16x32_bf16(a1, b, acc1[nt], 0, 0, 0);
        }
    }
    __syncthreads();   // At dead; RedS/RedQ alias it

    const int rb0 = row0 + w * 32 + quad * 4;
    const int rb1 = rb0 + 16;
    #pragma unroll
    for (int nt = 0; nt < 8; nt++) {
        int col = nt * 16 + lq;
        float bv = bias[col];
        float s = 0.f, q = 0.f;
        #pragma unroll
        for (int r = 0; r < 4; r++) {
            int gr = rb0 + r;
            if (gr < nRows) {
                float val = acc0[nt][r] + bv;
                size_t o = (size_t)gr * DD + col;
                if (OUT16) ((u16*)Out)[o] = f2bf(val);
                else       ((float*)Out)[o] = val;
                s += val; q += val * val;
            }
        }
        #pragma unroll
        for (int r = 0; r < 4; r++) {
            int gr = rb1 + r;
            if (gr < nRows) {
                float val = acc1[nt][r] + bv;
                size_t o = (size_t)gr * DD + col;
                if (OUT16) ((u16*)Out)[o] = f2bf(val);
                else       ((float*)Out)[o] = val;
                s += val; q += val * val;
            }
        }
        s += __shfl_xor(s, 16); q += __shfl_xor(q, 16);
        s += __shfl_xor(s, 32); q += __shfl_xor(q, 32);
        if (quad == 0) { RedS[w * 128 + col] = s; RedQ[w * 128 + col] = q; }
    }
    __syncthreads();
    if (t < 128) {
        float s = RedS[t] + RedS[128 + t] + RedS[256 + t] + RedS[384 + t];
        float q = RedQ[t] + RedQ[128 + t] + RedQ[256 + t] + RedQ[384 + t];
        atomicAdd(&ssum[t], s);
        atomicAdd(&ssq[t], q);
    }
}

// final h = relu(a*z2+b) -> A (fp32) + pool partials; last block divides.
__global__ __launch_bounds__(256, 4) void k_upool(
        const u16* __restrict__ Bz,
        const float* __restrict__ gIn, const float* __restrict__ bIn,
        const float* __restrict__ sIn, const float* __restrict__ qIn,
        const int* __restrict__ batch, float* __restrict__ A,
        float* __restrict__ gsum, const int* __restrict__ goff,
        float* __restrict__ outw, int* __restrict__ sem) {
    const int t = threadIdx.x;
    const int c = t & 127;
    const int half = t >> 7;           // rows half + 2i
    const int r0 = blockIdx.x * 64;
    float inv = 1.0f / (float)NN;
    float mu = sIn[c] * inv;
    float var = fmaxf(qIn[c] * inv - mu * mu, 0.f);
    float a = gIn[c] * rsqrtf(var + BN_EPS);
    float bb = bIn[c] - a * mu;
    float acc = 0.f;
    int curg = -1;
    for (int i = 0; i < 32; i++) {
        int r = r0 + half + 2 * i;
        if (r >= NN) break;
        int gg = batch[r];
        if (gg != curg) {
            if (curg >= 0) atomicAdd(&gsum[(size_t)curg * DD + c], acc);
            acc = 0.f; curg = gg;
        }
        float v = fmaxf(fmaf(a, bf2f(Bz[(size_t)r * DD + c]), bb), 0.f);
        A[(size_t)r * DD + c] = v;
        acc += v;
    }
    if (curg >= 0) atomicAdd(&gsum[(size_t)curg * DD + c], acc);

    __shared__ int lastF;
    if (t == 0) {
        __threadfence();
        lastF = (atomicAdd(&sem[1], 1) == gridDim.x - 1);
    }
    __syncthreads();
    if (!lastF) return;
    __threadfence();
    for (int i = t; i < NG * DD; i += 256) {
        int g = i >> 7;
        float cnt = fmaxf((float)(goff[g + 1] - goff[g]), 1.0f);
        outw[i] = atomicAdd(&gsum[i], 0.0f) / cnt;
    }
}

extern "C" void kernel_launch(void* const* d_in, const int* in_sizes, int n_in,
                              void* d_out, int out_size, void* d_ws, size_t ws_size,
                              hipStream_t stream) {
    const int* feat  = (const int*)d_in[0];
    const int* ei    = (const int*)d_in[1];
    const int* batch = (const int*)d_in[2];
    const void* vw   = d_in[3];
    const void* vb   = d_in[4];
    const void* demb = d_in[5];
    const void* w1   = d_in[6];
    const void* b1   = d_in[7];
    const void* g1   = d_in[8];
    const void* be1  = d_in[9];
    const void* w2   = d_in[10];
    const void* b2   = d_in[11];
    const void* g2   = d_in[12];
    const void* be2  = d_in[13];

    const int* src = ei;
    const int* dst = ei + NE;
    const size_t ND = (size_t)NN * DD;

    // ---- workspace layout ----
    float* pc     = (float*)d_ws;            // 3072: b1,b2,g1,be1,g2,be2
    int*   flag   = (int*)(pc + 3072);       // 64
    float* stats  = (float*)(flag + 64);     // 2048 [zero from here...]
    float* gsum   = stats + 2048;            // 8192
    int*   deg    = (int*)(gsum + 8192);     // NN
    int*   cursor = deg + NN;                // NN
    int*   sem    = cursor + NN;             // 64  [...to here]
    int*   bsum   = sem + 64;                // 256
    int*   goff   = bsum + 256;              // 128 (65 used)
    int*   rowptr = goff + 128;              // NN+64
    int*   colidx = rowptr + NN + 64;        // NE
    u16*   Wsw    = (u16*)(colidx + NE);     // 8*16384 u16
    u16*   B      = Wsw + 8 * 16384;         // ND bf16

    float* b1c  = pc;
    float* b2c  = pc + 512;
    float* g1c  = pc + 1024;
    float* be1c = pc + 1536;
    float* g2c  = pc + 2048;
    float* be2c = pc + 2560;
    float* sum1 = stats;          // [NL][128]
    float* sq1  = stats + 512;
    float* sum2 = stats + 1024;
    float* sq2  = stats + 1536;

    float* outw = (float*)d_out;             // [0, NG*DD): graph_feature
    float* A    = outw + (size_t)NG * DD;    // h region: fp32 z1 scratch, final h

    const int zwords = 2048 + 8192 + NN + NN + 64;  // stats, gsum, deg, cursor, sem
    const int gridND = (int)(ND / 256);             // 25000 exact
    const int gemmBlocks = (NN + 127) / 128;        // 391
    const int agBlocks   = (NN + 63) / 64;          // 782

    k_pre<<<2 + (zwords + 255) / 256, 256, 0, stream>>>(vb, flag, batch, goff,
                                                        stats, zwords);
    k_cvtswz<<<12 + 512, 256, 0, stream>>>(b1, b2, g1, be1, g2, be2, w1, w2,
                                           pc, Wsw, flag);
    k_deg<<<(NE + 255) / 256, 256, 0, stream>>>(dst, deg);
    k_scan12<<<NB, 256, 0, stream>>>(deg, bsum, sem);
    k_scan3init<<<NB + gridND, 256, 0, stream>>>(deg, bsum, rowptr,
                                                 feat, vw, vb, demb, B, flag);
    k_fill<<<(NE + 255) / 256, 256, 0, stream>>>(src, dst, rowptr, cursor, colidx);

    for (int l = 0; l < NL; l++) {
        const u16* W1l = Wsw + (size_t)l * 16384;
        const u16* W2l = Wsw + (size_t)(4 + l) * 16384;
        if (l == 0) {
            k_ag1<false><<<agBlocks, 256, 0, stream>>>(
                B, rowptr, colidx, W1l, b1c + l * 128,
                nullptr, nullptr, nullptr, nullptr,
                A, sum1 + l * 128, sq1 + l * 128);
        } else {
            k_ag1<true><<<agBlocks, 256, 0, stream>>>(
                B, rowptr, colidx, W1l, b1c + l * 128,
                g2c + (l - 1) * 128, be2c + (l - 1) * 128,
                sum2 + (l - 1) * 128, sq2 + (l - 1) * 128,
                A, sum1 + l * 128, sq1 + l * 128);
        }
        // GEMM2: A (fp32 z1) -> B (bf16 z2), affine from BN1 stats
        k_gemm<false, true, true><<<gemmBlocks, 256, 0, stream>>>(
            A, W2l, b2c + l * 128, g1c + l * 128, be1c + l * 128,
            sum1 + l * 128, sq1 + l * 128,
            B, sum2 + l * 128, sq2 + l * 128, NN);
    }
    k_upool<<<(NN + 63) / 64, 256, 0, stream>>>(
        B, g2c + 3 * 128, be2c + 3 * 128, sum2 + 3 * 128, sq2 + 3 * 128,
        batch, A, gsum, goff, outw, sem);
}

// Round 2
// 643.487 us; speedup vs baseline: 1.2065x; 1.2065x over previous
//
#include <hip/hip_runtime.h>

#define NN 50000
#define NE 500000
#define DD 128
#define NL 4
#define NG 64
#define FIXED_DIM 10000
#define BN_EPS 1e-5f
#define NB 196   // ceil(NN/256)

typedef unsigned short u16;
typedef unsigned int u32;
typedef __attribute__((ext_vector_type(8))) short bf16x8;
typedef __attribute__((ext_vector_type(4))) float f32x4;

__device__ __forceinline__ float bf2f(u16 u) {
    return __uint_as_float(((u32)u) << 16);
}
__device__ __forceinline__ u16 f2bf(float f) {
    u32 u = __float_as_uint(f);
    return (u16)((u + 0x7FFFu + ((u >> 16) & 1u)) >> 16);
}
// adaptive float-INPUT load (isbf: bf16 vs fp32)
__device__ __forceinline__ float ldf(const void* p, size_t i, int isbf) {
    return isbf ? bf2f(((const u16*)p)[i]) : ((const float*)p)[i];
}

// fused preamble: block 0 = dtype probe; block 1 = goff binary search;
// blocks 2+ = zero of [stats .. sem] region (no cross-block deps).
__global__ void k_pre(const void* __restrict__ vb, int* __restrict__ flag,
                      const int* __restrict__ batch, int* __restrict__ goff,
                      float* __restrict__ zbase, int zwords) {
    int b = blockIdx.x, t = threadIdx.x;
    if (b == 0) {
        __shared__ int ok[256];
        float v = (t < 128) ? bf2f(((const u16*)vb)[t]) : 0.f;
        ok[t] = (t < 128) ? ((fabsf(v) < 1000.f) ? 1 : 0) : 1;
        __syncthreads();
        for (int off = 128; off; off >>= 1) {
            if (t < off) ok[t] &= ok[t + off];
            __syncthreads();
        }
        if (t == 0) *flag = ok[0];
    } else if (b == 1) {
        if (t <= NG) {
            int lo = 0, hi = NN;
            while (lo < hi) {
                int mid = (lo + hi) >> 1;
                if (batch[mid] < t) lo = mid + 1; else hi = mid;
            }
            goff[t] = lo;
        }
    } else {
        int i = (b - 2) * 256 + t;
        if (i < zwords) zbase[i] = 0.f;
    }
}

// merged: blocks 0..11 convert 6 per-layer param tensors (6*NL*DD = 3072)
// to fp32; blocks 12.. pre-swizzle 8 weight matrices into MFMA B-frag order:
// Wsw[m*16384 + ((nt*4+ks)*64 + lane)*8 + j]
//   = W_m[ks*32 + (lane>>4)*8 + j][nt*16 + (lane&15)]   (bf16)
__global__ void k_cvtswz(const void* b1, const void* b2, const void* g1,
                         const void* be1, const void* g2, const void* be2,
                         const void* __restrict__ w1, const void* __restrict__ w2,
                         float* __restrict__ pc, u16* __restrict__ Wsw,
                         const int* __restrict__ flag) {
    int b = blockIdx.x, tt = threadIdx.x;
    if (b < 12) {
        int t = b * 256 + tt;            // < 3072 exactly
        int p = t >> 9, j = t & 511;
        const void* s = (p == 0) ? b1 : (p == 1) ? b2 : (p == 2) ? g1
                      : (p == 3) ? be1 : (p == 4) ? g2 : be2;
        pc[t] = ldf(s, j, *flag);
    } else {
        int t = (b - 12) * 256 + tt;     // < 131072 exactly
        int m    = t >> 14;
        int idx  = t & 16383;
        int nt   = idx >> 11;
        int ks   = (idx >> 9) & 3;
        int lane = (idx >> 3) & 63;
        int j    = idx & 7;
        int row = ks * 32 + (lane >> 4) * 8 + j;
        int col = nt * 16 + (lane & 15);
        const void* src = (m < 4) ? w1 : w2;
        size_t off = (size_t)(m & 3) * DD * DD + (size_t)row * DD + col;
        Wsw[t] = f2bf(ldf(src, off, *flag));
    }
}

__global__ void k_deg(const int* __restrict__ dst, int* __restrict__ deg) {
    int i = blockIdx.x * 256 + threadIdx.x;
    if (i < NE) atomicAdd(&deg[dst[i]], 1);
}

// scan stage 1 + (last-block) stage 2: per-block sums -> exclusive scan of bsum.
// Device-scope atomics for cross-XCD visibility within the kernel.
__global__ void k_scan12(const int* __restrict__ deg, int* __restrict__ bsum,
                         int* __restrict__ sem) {
    __shared__ int S[256];
    __shared__ int lastB;
    int b = blockIdx.x, t = threadIdx.x;
    int i = b * 256 + t;
    S[t] = (i < NN) ? deg[i] : 0;
    __syncthreads();
    for (int off = 128; off; off >>= 1) {
        if (t < off) S[t] += S[t + off];
        __syncthreads();
    }
    if (t == 0) {
        atomicExch(&bsum[b], S[0]);
        __threadfence();
        lastB = (atomicAdd(&sem[0], 1) == gridDim.x - 1);
    }
    __syncthreads();
    if (!lastB) return;
    __threadfence();
    int v = (t < NB) ? atomicAdd(&bsum[t], 0) : 0;
    S[t] = v;
    __syncthreads();
    for (int off = 1; off < 256; off <<= 1) {
        int x = (t >= off) ? S[t - off] : 0;
        __syncthreads();
        S[t] += x;
        __syncthreads();
    }
    if (t < NB) bsum[t] = S[t] - v;                 // exclusive
}

// merged: blocks 0..NB-1 finish the rowptr scan; blocks NB.. compute
// h0 = vw[feat] + vb + deg_emb[min(deg,1000)] -> B (bf16).
__global__ void k_scan3init(const int* __restrict__ deg, const int* __restrict__ bsum,
                            int* __restrict__ rowptr,
                            const int* __restrict__ feat, const void* __restrict__ vw,
                            const void* __restrict__ vb, const void* __restrict__ demb,
                            u16* __restrict__ B, const int* __restrict__ flag) {
    __shared__ int S[256];
    int b = blockIdx.x, t = threadIdx.x;
    if (b < NB) {
        int i = b * 256 + t;
        int v = (i < NN) ? deg[i] : 0;
        S[t] = v;
        __syncthreads();
        for (int off = 1; off < 256; off <<= 1) {
            int x = (t >= off) ? S[t - off] : 0;
            __syncthreads();
            S[t] += x;
            __syncthreads();
        }
        if (i < NN) rowptr[i] = bsum[b] + S[t] - v;
        if (i == NN - 1) rowptr[NN] = bsum[b] + S[t];   // == NE
    } else {
        int idx = (b - NB) * 256 + t;
        if (idx >= NN * DD) return;
        int n = idx >> 7, c = idx & 127;
        int isbf = *flag;
        int f = feat[n] % FIXED_DIM;
        int dg = min(deg[n], 1000);
        B[idx] = f2bf(ldf(vw, (size_t)f * DD + c, isbf)
                    + ldf(vb, c, isbf)
                    + ldf(demb, (size_t)dg * DD + c, isbf));
    }
}

__global__ void k_fill(const int* __restrict__ src, const int* __restrict__ dst,
                       const int* __restrict__ rowptr, int* __restrict__ cursor,
                       int* __restrict__ colidx) {
    int e = blockIdx.x * 256 + threadIdx.x;
    if (e >= NE) return;
    int d = dst[e];
    int p = atomicAdd(&cursor[d], 1);
    colidx[rowptr[d] + p] = src[e];
}

// GIN aggregation with fused h-recompute, bf16 out (PROVEN round-0 structure:
// 1 row/wave, 2 cols/lane, occupancy 8 -> max TLP for the latency-bound gather).
//   f(x) = AFF ? relu(a[c]*x + b[c]) : x   (a,b from prev layer's BN2 stats)
//   Agg[n] = f(B[n]) + sum_{j in row n} f(B[colidx[j]])
template <bool AFF>
__global__ __launch_bounds__(256, 8) void k_aggr(
        const u16* __restrict__ B, const int* __restrict__ rowptr,
        const int* __restrict__ colidx,
        const float* __restrict__ gIn, const float* __restrict__ bIn,
        const float* __restrict__ sIn, const float* __restrict__ qIn,
        u16* __restrict__ Agg) {
    int n = blockIdx.x * 4 + (threadIdx.x >> 6);
    if (n >= NN) return;
    int c = (threadIdx.x & 63) * 2;
    float a0 = 1.f, b0 = 0.f, a1 = 1.f, b1 = 0.f;
    if (AFF) {
        float inv = 1.0f / (float)NN;
        float mu0 = sIn[c] * inv, mu1 = sIn[c + 1] * inv;
        float v0 = fmaxf(qIn[c] * inv - mu0 * mu0, 0.f);
        float v1 = fmaxf(qIn[c + 1] * inv - mu1 * mu1, 0.f);
        a0 = gIn[c] * rsqrtf(v0 + BN_EPS);
        a1 = gIn[c + 1] * rsqrtf(v1 + BN_EPS);
        b0 = bIn[c] - a0 * mu0;
        b1 = bIn[c + 1] - a1 * mu1;
    }
    u32 w = *(const u32*)&B[(size_t)n * DD + c];
    float x0 = bf2f((u16)(w & 0xFFFF)), x1 = bf2f((u16)(w >> 16));
    float s0 = AFF ? fmaxf(fmaf(a0, x0, b0), 0.f) : x0;
    float s1 = AFF ? fmaxf(fmaf(a1, x1, b1), 0.f) : x1;
    int lo = rowptr[n], hi = rowptr[n + 1];
    int j = lo;
    for (; j + 4 <= hi; j += 4) {
        int m0 = colidx[j], m1 = colidx[j + 1];
        int m2 = colidx[j + 2], m3 = colidx[j + 3];
        u32 w0 = *(const u32*)&B[(size_t)m0 * DD + c];
        u32 w1v = *(const u32*)&B[(size_t)m1 * DD + c];
        u32 w2v = *(const u32*)&B[(size_t)m2 * DD + c];
        u32 w3v = *(const u32*)&B[(size_t)m3 * DD + c];
        float y;
        y = bf2f((u16)(w0 & 0xFFFF)); s0 += AFF ? fmaxf(fmaf(a0, y, b0), 0.f) : y;
        y = bf2f((u16)(w0 >> 16));    s1 += AFF ? fmaxf(fmaf(a1, y, b1), 0.f) : y;
        y = bf2f((u16)(w1v & 0xFFFF)); s0 += AFF ? fmaxf(fmaf(a0, y, b0), 0.f) : y;
        y = bf2f((u16)(w1v >> 16));    s1 += AFF ? fmaxf(fmaf(a1, y, b1), 0.f) : y;
        y = bf2f((u16)(w2v & 0xFFFF)); s0 += AFF ? fmaxf(fmaf(a0, y, b0), 0.f) : y;
        y = bf2f((u16)(w2v >> 16));    s1 += AFF ? fmaxf(fmaf(a1, y, b1), 0.f) : y;
        y = bf2f((u16)(w3v & 0xFFFF)); s0 += AFF ? fmaxf(fmaf(a0, y, b0), 0.f) : y;
        y = bf2f((u16)(w3v >> 16));    s1 += AFF ? fmaxf(fmaf(a1, y, b1), 0.f) : y;
    }
    for (; j < hi; j++) {
        int m = colidx[j];
        w = *(const u32*)&B[(size_t)m * DD + c];
        x0 = bf2f((u16)(w & 0xFFFF)); x1 = bf2f((u16)(w >> 16));
        s0 += AFF ? fmaxf(fmaf(a0, x0, b0), 0.f) : x0;
        s1 += AFF ? fmaxf(fmaf(a1, x1, b1), 0.f) : x1;
    }
    *(u32*)&Agg[(size_t)n * DD + c] = ((u32)f2bf(s1) << 16) | (u32)f2bf(s0);
}

// ---- MFMA GEMM, 64 rows x 128 cols per block (782 blocks, 3 blocks/CU) ----
// Out = f(In) @ W + bias; f = AFF ? relu(aff*x+b) : id.
// Wave w owns rows w*16..w*16+15 (one M-tile); 32 MFMAs/wave.
// LDS: Wl 32K + At 17.4K + affS 1K = 50.2 KB -> 3 blocks/CU.
// Red buffers alias At (dead after MFMA loop). In-place safe (block-local rows).
template <bool IN16, bool OUT16, bool AFF>
__global__ __launch_bounds__(256, 3) void k_gemm(
        const void* In, const u16* __restrict__ Wsw,
        const float* __restrict__ bias,
        const float* __restrict__ gIn, const float* __restrict__ bIn,
        const float* __restrict__ sIn, const float* __restrict__ qIn,
        void* Out, float* __restrict__ ssum, float* __restrict__ ssq,
        int nRows) {
    __shared__ u16 Wl[16384];          // 32 KB swizzled W
    __shared__ u16 At[64 * 136];       // 17.4 KB bf16 A-tile, pitch 136
    __shared__ float affS[256];        // 1 KB
    float* RedS = (float*)At;          // alias At after MFMA loop
    float* RedQ = RedS + 512;
    const int t = threadIdx.x;
    const int row0 = blockIdx.x * 64;

    if (AFF) {
        if (t < 128) {
            float inv = 1.0f / (float)NN;
            float mu = sIn[t] * inv;
            float var = fmaxf(qIn[t] * inv - mu * mu, 0.f);
            float a = gIn[t] * rsqrtf(var + BN_EPS);
            affS[t] = a;
            affS[128 + t] = bIn[t] - a * mu;
        }
        __syncthreads();
    }

    // stage swizzled W: 2048 uint4 blockwide
    {
        const uint4* s = (const uint4*)Wsw;
        uint4* d = (uint4*)Wl;
        #pragma unroll
        for (int i = 0; i < 8; i++) d[t + i * 256] = s[t + i * 256];
    }
    // stage A-tile (64 rows)
    if (IN16) {
        #pragma unroll
        for (int i = t; i < 1024; i += 256) {
            int r  = i >> 4;
            int c8 = (i & 15) * 8;
            int gr = row0 + r;
            uint4 v = make_uint4(0u, 0u, 0u, 0u);
            if (gr < nRows) v = *(const uint4*)&((const u16*)In)[(size_t)gr * DD + c8];
            *(uint4*)&At[r * 136 + c8] = v;
        }
    } else {
        #pragma unroll
        for (int i = t; i < 2048; i += 256) {
            int r  = i >> 5;
            int c4 = (i & 31) * 4;
            int gr = row0 + r;
            float4 v = make_float4(0.f, 0.f, 0.f, 0.f);
            if (gr < nRows) {
                v = *(const float4*)&((const float*)In)[(size_t)gr * DD + c4];
                if (AFF) {
                    v.x = fmaxf(fmaf(affS[c4 + 0], v.x, affS[128 + c4 + 0]), 0.f);
                    v.y = fmaxf(fmaf(affS[c4 + 1], v.y, affS[128 + c4 + 1]), 0.f);
                    v.z = fmaxf(fmaf(affS[c4 + 2], v.z, affS[128 + c4 + 2]), 0.f);
                    v.w = fmaxf(fmaf(affS[c4 + 3], v.w, affS[128 + c4 + 3]), 0.f);
                }
            }
            ushort4 o;
            o.x = f2bf(v.x); o.y = f2bf(v.y); o.z = f2bf(v.z); o.w = f2bf(v.w);
            *(ushort4*)&At[r * 136 + c4] = o;
        }
    }
    __syncthreads();

    const int w    = t >> 6;
    const int ln   = t & 63;
    const int quad = ln >> 4;
    const int lq   = ln & 15;

    f32x4 acc[8];
    #pragma unroll
    for (int nt = 0; nt < 8; nt++) acc[nt] = (f32x4){0.f, 0.f, 0.f, 0.f};

    const u16* aRow = &At[(w * 16 + lq) * 136 + quad * 8];
    #pragma unroll
    for (int ks = 0; ks < 4; ks++) {
        bf16x8 a = *(const bf16x8*)&aRow[ks * 32];
        #pragma unroll
        for (int nt = 0; nt < 8; nt++) {
            bf16x8 b = *(const bf16x8*)&Wl[((nt * 4 + ks) * 64 + ln) * 8];
            acc[nt] = __builtin_amdgcn_mfma_f32_16x16x32_bf16(a, b, acc[nt], 0, 0, 0);
        }
    }
    __syncthreads();   // At dead; RedS/RedQ alias it

    // epilogue: D[row=quad*4+r][col=nt*16+lq]
    const int rb = row0 + w * 16 + quad * 4;
    #pragma unroll
    for (int nt = 0; nt < 8; nt++) {
        int col = nt * 16 + lq;
        float bv = bias[col];
        float s = 0.f, q = 0.f;
        #pragma unroll
        for (int r = 0; r < 4; r++) {
            int gr = rb + r;
            if (gr < nRows) {
                float val = acc[nt][r] + bv;
                size_t o = (size_t)gr * DD + col;
                if (OUT16) ((u16*)Out)[o] = f2bf(val);
                else       ((float*)Out)[o] = val;
                s += val; q += val * val;
            }
        }
        s += __shfl_xor(s, 16); q += __shfl_xor(q, 16);
        s += __shfl_xor(s, 32); q += __shfl_xor(q, 32);
        if (quad == 0) { RedS[w * 128 + col] = s; RedQ[w * 128 + col] = q; }
    }
    __syncthreads();
    if (t < 128) {
        float s = RedS[t] + RedS[128 + t] + RedS[256 + t] + RedS[384 + t];
        float q = RedQ[t] + RedQ[128 + t] + RedQ[256 + t] + RedQ[384 + t];
        atomicAdd(&ssum[t], s);
        atomicAdd(&ssq[t], q);
    }
}

// final h = relu(a*z2+b) -> A (fp32) + pool partials; last block divides.
__global__ __launch_bounds__(256, 4) void k_upool(
        const u16* __restrict__ Bz,
        const float* __restrict__ gIn, const float* __restrict__ bIn,
        const float* __restrict__ sIn, const float* __restrict__ qIn,
        const int* __restrict__ batch, float* __restrict__ A,
        float* __restrict__ gsum, const int* __restrict__ goff,
        float* __restrict__ outw, int* __restrict__ sem) {
    const int t = threadIdx.x;
    const int c = t & 127;
    const int half = t >> 7;           // rows half + 2i
    const int r0 = blockIdx.x * 64;
    float inv = 1.0f / (float)NN;
    float mu = sIn[c] * inv;
    float var = fmaxf(qIn[c] * inv - mu * mu, 0.f);
    float a = gIn[c] * rsqrtf(var + BN_EPS);
    float bb = bIn[c] - a * mu;
    float acc = 0.f;
    int curg = -1;
    for (int i = 0; i < 32; i++) {
        int r = r0 + half + 2 * i;
        if (r >= NN) break;
        int gg = batch[r];
        if (gg != curg) {
            if (curg >= 0) atomicAdd(&gsum[(size_t)curg * DD + c], acc);
            acc = 0.f; curg = gg;
        }
        float v = fmaxf(fmaf(a, bf2f(Bz[(size_t)r * DD + c]), bb), 0.f);
        A[(size_t)r * DD + c] = v;
        acc += v;
    }
    if (curg >= 0) atomicAdd(&gsum[(size_t)curg * DD + c], acc);

    __shared__ int lastF;
    if (t == 0) {
        __threadfence();
        lastF = (atomicAdd(&sem[1], 1) == gridDim.x - 1);
    }
    __syncthreads();
    if (!lastF) return;
    __threadfence();
    for (int i = t; i < NG * DD; i += 256) {
        int g = i >> 7;
        float cnt = fmaxf((float)(goff[g + 1] - goff[g]), 1.0f);
        outw[i] = atomicAdd(&gsum[i], 0.0f) / cnt;
    }
}

extern "C" void kernel_launch(void* const* d_in, const int* in_sizes, int n_in,
                              void* d_out, int out_size, void* d_ws, size_t ws_size,
                              hipStream_t stream) {
    const int* feat  = (const int*)d_in[0];
    const int* ei    = (const int*)d_in[1];
    const int* batch = (const int*)d_in[2];
    const void* vw   = d_in[3];
    const void* vb   = d_in[4];
    const void* demb = d_in[5];
    const void* w1   = d_in[6];
    const void* b1   = d_in[7];
    const void* g1   = d_in[8];
    const void* be1  = d_in[9];
    const void* w2   = d_in[10];
    const void* b2   = d_in[11];
    const void* g2   = d_in[12];
    const void* be2  = d_in[13];

    const int* src = ei;
    const int* dst = ei + NE;
    const size_t ND = (size_t)NN * DD;

    // ---- workspace layout ----
    float* pc     = (float*)d_ws;            // 3072: b1,b2,g1,be1,g2,be2
    int*   flag   = (int*)(pc + 3072);       // 64
    float* stats  = (float*)(flag + 64);     // 2048 [zero from here...]
    float* gsum   = stats + 2048;            // 8192
    int*   deg    = (int*)(gsum + 8192);     // NN
    int*   cursor = deg + NN;                // NN
    int*   sem    = cursor + NN;             // 64  [...to here]
    int*   bsum   = sem + 64;                // 256
    int*   goff   = bsum + 256;              // 128 (65 used)
    int*   rowptr = goff + 128;              // NN+64
    int*   colidx = rowptr + NN + 64;        // NE
    u16*   Wsw    = (u16*)(colidx + NE);     // 8*16384 u16
    u16*   B      = Wsw + 8 * 16384;         // ND bf16
    u16*   Agg16  = B + ND;                  // ND bf16

    float* b1c  = pc;
    float* b2c  = pc + 512;
    float* g1c  = pc + 1024;
    float* be1c = pc + 1536;
    float* g2c  = pc + 2048;
    float* be2c = pc + 2560;
    float* sum1 = stats;          // [NL][128]
    float* sq1  = stats + 512;
    float* sum2 = stats + 1024;
    float* sq2  = stats + 1536;

    float* outw = (float*)d_out;             // [0, NG*DD): graph_feature
    float* A    = outw + (size_t)NG * DD;    // h region: fp32 z1 scratch, final h

    const int zwords = 2048 + 8192 + NN + NN + 64;  // stats, gsum, deg, cursor, sem
    const int gridND = (int)(ND / 256);             // 25000 exact
    const int gemmBlocks = (NN + 63) / 64;          // 782
    const int aggrBlocks = (NN + 3) / 4;            // 12500

    k_pre<<<2 + (zwords + 255) / 256, 256, 0, stream>>>(vb, flag, batch, goff,
                                                        stats, zwords);
    k_cvtswz<<<12 + 512, 256, 0, stream>>>(b1, b2, g1, be1, g2, be2, w1, w2,
                                           pc, Wsw, flag);
    k_deg<<<(NE + 255) / 256, 256, 0, stream>>>(dst, deg);
    k_scan12<<<NB, 256, 0, stream>>>(deg, bsum, sem);
    k_scan3init<<<NB + gridND, 256, 0, stream>>>(deg, bsum, rowptr,
                                                 feat, vw, vb, demb, B, flag);
    k_fill<<<(NE + 255) / 256, 256, 0, stream>>>(src, dst, rowptr, cursor, colidx);

    for (int l = 0; l < NL; l++) {
        const u16* W1l = Wsw + (size_t)l * 16384;
        const u16* W2l = Wsw + (size_t)(4 + l) * 16384;
        if (l == 0) {
            k_aggr<false><<<aggrBlocks, 256, 0, stream>>>(
                B, rowptr, colidx, nullptr, nullptr, nullptr, nullptr, Agg16);
        } else {
            k_aggr<true><<<aggrBlocks, 256, 0, stream>>>(
                B, rowptr, colidx, g2c + (l - 1) * 128, be2c + (l - 1) * 128,
                sum2 + (l - 1) * 128, sq2 + (l - 1) * 128, Agg16);
        }
        // GEMM1: Agg16 (bf16) -> A (fp32 z1)
        k_gemm<true, false, false><<<gemmBlocks, 256, 0, stream>>>(
            Agg16, W1l, b1c + l * 128, nullptr, nullptr, nullptr, nullptr,
            A, sum1 + l * 128, sq1 + l * 128, NN);
        // GEMM2: A (fp32 z1) -> B (bf16 z2), affine from BN1 stats
        k_gemm<false, true, true><<<gemmBlocks, 256, 0, stream>>>(
            A, W2l, b2c + l * 128, g1c + l * 128, be1c + l * 128,
            sum1 + l * 128, sq1 + l * 128,
            B, sum2 + l * 128, sq2 + l * 128, NN);
    }
    k_upool<<<(NN + 63) / 64, 256, 0, stream>>>(
        B, g2c + 3 * 128, be2c + 3 * 128, sum2 + 3 * 128, sq2 + 3 * 128,
        batch, A, gsum, goff, outw, sem);
}

// Round 3
// 557.537 us; speedup vs baseline: 1.3925x; 1.1542x over previous
//
#include <hip/hip_runtime.h>

#define NN 50000
#define NE 500000
#define DD 128
#define NL 4
#define NG 64
#define FIXED_DIM 10000
#define BN_EPS 1e-5f
#define NB 196   // ceil(NN/256)

typedef unsigned short u16;
typedef unsigned int u32;
typedef __attribute__((ext_vector_type(8))) short bf16x8;
typedef __attribute__((ext_vector_type(4))) float f32x4;

__device__ __forceinline__ float bf2f(u16 u) {
    return __uint_as_float(((u32)u) << 16);
}
__device__ __forceinline__ u16 f2bf(float f) {
    u32 u = __float_as_uint(f);
    return (u16)((u + 0x7FFFu + ((u >> 16) & 1u)) >> 16);
}
// adaptive float-INPUT load (isbf: bf16 vs fp32)
__device__ __forceinline__ float ldf(const void* p, size_t i, int isbf) {
    return isbf ? bf2f(((const u16*)p)[i]) : ((const float*)p)[i];
}

// fused preamble: block 0 = dtype probe; block 1 = goff binary search;
// blocks 2+ = zero of [stats .. sem] region (no cross-block deps).
__global__ void k_pre(const void* __restrict__ vb, int* __restrict__ flag,
                      const int* __restrict__ batch, int* __restrict__ goff,
                      float* __restrict__ zbase, int zwords) {
    int b = blockIdx.x, t = threadIdx.x;
    if (b == 0) {
        __shared__ int ok[256];
        float v = (t < 128) ? bf2f(((const u16*)vb)[t]) : 0.f;
        ok[t] = (t < 128) ? ((fabsf(v) < 1000.f) ? 1 : 0) : 1;
        __syncthreads();
        for (int off = 128; off; off >>= 1) {
            if (t < off) ok[t] &= ok[t + off];
            __syncthreads();
        }
        if (t == 0) *flag = ok[0];
    } else if (b == 1) {
        if (t <= NG) {
            int lo = 0, hi = NN;
            while (lo < hi) {
                int mid = (lo + hi) >> 1;
                if (batch[mid] < t) lo = mid + 1; else hi = mid;
            }
            goff[t] = lo;
        }
    } else {
        int i = (b - 2) * 256 + t;
        if (i < zwords) zbase[i] = 0.f;
    }
}

// merged: blocks 0..11 convert 6 per-layer param tensors (6*NL*DD = 3072)
// to fp32; blocks 12.. pre-swizzle 8 weight matrices into MFMA B-frag order:
// Wsw[m*16384 + ((nt*4+ks)*64 + lane)*8 + j]
//   = W_m[ks*32 + (lane>>4)*8 + j][nt*16 + (lane&15)]   (bf16)
__global__ void k_cvtswz(const void* b1, const void* b2, const void* g1,
                         const void* be1, const void* g2, const void* be2,
                         const void* __restrict__ w1, const void* __restrict__ w2,
                         float* __restrict__ pc, u16* __restrict__ Wsw,
                         const int* __restrict__ flag) {
    int b = blockIdx.x, tt = threadIdx.x;
    if (b < 12) {
        int t = b * 256 + tt;            // < 3072 exactly
        int p = t >> 9, j = t & 511;
        const void* s = (p == 0) ? b1 : (p == 1) ? b2 : (p == 2) ? g1
                      : (p == 3) ? be1 : (p == 4) ? g2 : be2;
        pc[t] = ldf(s, j, *flag);
    } else {
        int t = (b - 12) * 256 + tt;     // < 131072 exactly
        int m    = t >> 14;
        int idx  = t & 16383;
        int nt   = idx >> 11;
        int ks   = (idx >> 9) & 3;
        int lane = (idx >> 3) & 63;
        int j    = idx & 7;
        int row = ks * 32 + (lane >> 4) * 8 + j;
        int col = nt * 16 + (lane & 15);
        const void* src = (m < 4) ? w1 : w2;
        size_t off = (size_t)(m & 3) * DD * DD + (size_t)row * DD + col;
        Wsw[t] = f2bf(ldf(src, off, *flag));
    }
}

__global__ void k_deg(const int* __restrict__ dst, int* __restrict__ deg) {
    int i = blockIdx.x * 256 + threadIdx.x;
    if (i < NE) atomicAdd(&deg[dst[i]], 1);
}

// scan stage 1 + (last-block) stage 2: per-block sums -> exclusive scan of bsum.
// Device-scope atomics for cross-XCD visibility within the kernel.
__global__ void k_scan12(const int* __restrict__ deg, int* __restrict__ bsum,
                         int* __restrict__ sem) {
    __shared__ int S[256];
    __shared__ int lastB;
    int b = blockIdx.x, t = threadIdx.x;
    int i = b * 256 + t;
    S[t] = (i < NN) ? deg[i] : 0;
    __syncthreads();
    for (int off = 128; off; off >>= 1) {
        if (t < off) S[t] += S[t + off];
        __syncthreads();
    }
    if (t == 0) {
        atomicExch(&bsum[b], S[0]);
        __threadfence();
        lastB = (atomicAdd(&sem[0], 1) == gridDim.x - 1);
    }
    __syncthreads();
    if (!lastB) return;
    __threadfence();
    int v = (t < NB) ? atomicAdd(&bsum[t], 0) : 0;
    S[t] = v;
    __syncthreads();
    for (int off = 1; off < 256; off <<= 1) {
        int x = (t >= off) ? S[t - off] : 0;
        __syncthreads();
        S[t] += x;
        __syncthreads();
    }
    if (t < NB) bsum[t] = S[t] - v;                 // exclusive
}

// merged: blocks 0..NB-1 finish the rowptr scan; blocks NB.. compute
// h0 = vw[feat] + vb + deg_emb[min(deg,1000)] -> B (bf16).
__global__ void k_scan3init(const int* __restrict__ deg, const int* __restrict__ bsum,
                            int* __restrict__ rowptr,
                            const int* __restrict__ feat, const void* __restrict__ vw,
                            const void* __restrict__ vb, const void* __restrict__ demb,
                            u16* __restrict__ B, const int* __restrict__ flag) {
    __shared__ int S[256];
    int b = blockIdx.x, t = threadIdx.x;
    if (b < NB) {
        int i = b * 256 + t;
        int v = (i < NN) ? deg[i] : 0;
        S[t] = v;
        __syncthreads();
        for (int off = 1; off < 256; off <<= 1) {
            int x = (t >= off) ? S[t - off] : 0;
            __syncthreads();
            S[t] += x;
            __syncthreads();
        }
        if (i < NN) rowptr[i] = bsum[b] + S[t] - v;
        if (i == NN - 1) rowptr[NN] = bsum[b] + S[t];   // == NE
    } else {
        int idx = (b - NB) * 256 + t;
        if (idx >= NN * DD) return;
        int n = idx >> 7, c = idx & 127;
        int isbf = *flag;
        int f = feat[n] % FIXED_DIM;
        int dg = min(deg[n], 1000);
        B[idx] = f2bf(ldf(vw, (size_t)f * DD + c, isbf)
                    + ldf(vb, c, isbf)
                    + ldf(demb, (size_t)dg * DD + c, isbf));
    }
}

__global__ void k_fill(const int* __restrict__ src, const int* __restrict__ dst,
                       const int* __restrict__ rowptr, int* __restrict__ cursor,
                       int* __restrict__ colidx) {
    int e = blockIdx.x * 256 + threadIdx.x;
    if (e >= NE) return;
    int d = dst[e];
    int p = atomicAdd(&cursor[d], 1);
    colidx[rowptr[d] + p] = src[e];
}

// GIN aggregation with fused h-recompute, bf16 out (proven structure:
// 1 row/wave, 2 cols/lane, occupancy 8 -> max TLP for the latency-bound gather).
//   f(x) = AFF ? relu(a[c]*x + b[c]) : x   (a,b from prev layer's BN2 stats)
//   Agg[n] = f(B[n]) + sum_{j in row n} f(B[colidx[j]])
template <bool AFF>
__global__ __launch_bounds__(256, 8) void k_aggr(
        const u16* __restrict__ B, const int* __restrict__ rowptr,
        const int* __restrict__ colidx,
        const float* __restrict__ gIn, const float* __restrict__ bIn,
        const float* __restrict__ sIn, const float* __restrict__ qIn,
        u16* __restrict__ Agg) {
    int n = blockIdx.x * 4 + (threadIdx.x >> 6);
    if (n >= NN) return;
    int c = (threadIdx.x & 63) * 2;
    float a0 = 1.f, b0 = 0.f, a1 = 1.f, b1 = 0.f;
    if (AFF) {
        float inv = 1.0f / (float)NN;
        float mu0 = sIn[c] * inv, mu1 = sIn[c + 1] * inv;
        float v0 = fmaxf(qIn[c] * inv - mu0 * mu0, 0.f);
        float v1 = fmaxf(qIn[c + 1] * inv - mu1 * mu1, 0.f);
        a0 = gIn[c] * rsqrtf(v0 + BN_EPS);
        a1 = gIn[c + 1] * rsqrtf(v1 + BN_EPS);
        b0 = bIn[c] - a0 * mu0;
        b1 = bIn[c + 1] - a1 * mu1;
    }
    u32 w = *(const u32*)&B[(size_t)n * DD + c];
    float x0 = bf2f((u16)(w & 0xFFFF)), x1 = bf2f((u16)(w >> 16));
    float s0 = AFF ? fmaxf(fmaf(a0, x0, b0), 0.f) : x0;
    float s1 = AFF ? fmaxf(fmaf(a1, x1, b1), 0.f) : x1;
    int lo = rowptr[n], hi = rowptr[n + 1];
    int j = lo;
    for (; j + 4 <= hi; j += 4) {
        int m0 = colidx[j], m1 = colidx[j + 1];
        int m2 = colidx[j + 2], m3 = colidx[j + 3];
        u32 w0 = *(const u32*)&B[(size_t)m0 * DD + c];
        u32 w1v = *(const u32*)&B[(size_t)m1 * DD + c];
        u32 w2v = *(const u32*)&B[(size_t)m2 * DD + c];
        u32 w3v = *(const u32*)&B[(size_t)m3 * DD + c];
        float y;
        y = bf2f((u16)(w0 & 0xFFFF)); s0 += AFF ? fmaxf(fmaf(a0, y, b0), 0.f) : y;
        y = bf2f((u16)(w0 >> 16));    s1 += AFF ? fmaxf(fmaf(a1, y, b1), 0.f) : y;
        y = bf2f((u16)(w1v & 0xFFFF)); s0 += AFF ? fmaxf(fmaf(a0, y, b0), 0.f) : y;
        y = bf2f((u16)(w1v >> 16));    s1 += AFF ? fmaxf(fmaf(a1, y, b1), 0.f) : y;
        y = bf2f((u16)(w2v & 0xFFFF)); s0 += AFF ? fmaxf(fmaf(a0, y, b0), 0.f) : y;
        y = bf2f((u16)(w2v >> 16));    s1 += AFF ? fmaxf(fmaf(a1, y, b1), 0.f) : y;
        y = bf2f((u16)(w3v & 0xFFFF)); s0 += AFF ? fmaxf(fmaf(a0, y, b0), 0.f) : y;
        y = bf2f((u16)(w3v >> 16));    s1 += AFF ? fmaxf(fmaf(a1, y, b1), 0.f) : y;
    }
    for (; j < hi; j++) {
        int m = colidx[j];
        w = *(const u32*)&B[(size_t)m * DD + c];
        x0 = bf2f((u16)(w & 0xFFFF)); x1 = bf2f((u16)(w >> 16));
        s0 += AFF ? fmaxf(fmaf(a0, x0, b0), 0.f) : x0;
        s1 += AFF ? fmaxf(fmaf(a1, x1, b1), 0.f) : x1;
    }
    *(u32*)&Agg[(size_t)n * DD + c] = ((u32)f2bf(s1) << 16) | (u32)f2bf(s0);
}

// ---- MFMA GEMM, 128 rows x 128 cols per block (391 blocks) ----
// PROVEN round-0 config: fewer, larger blocks win for this K=128,
// staging/epilogue-dominated GEMM (64-row variant measured +14us/dispatch).
// Out = f(In) @ W + bias; f = AFF ? relu(aff*x+b) : id.
// Wave w owns rows w*32..w*32+31 (2 M-tiles); 64 MFMAs/wave.
// LDS: Wl 32K + At 34.8K + affS 1K = 68.6 KB -> 2 blocks/CU.
// Red buffers alias At (dead after MFMA loop). In-place safe (block-local rows).
template <bool IN16, bool OUT16, bool AFF>
__global__ __launch_bounds__(256, 2) void k_gemm(
        const void* In, const u16* __restrict__ Wsw,
        const float* __restrict__ bias,
        const float* __restrict__ gIn, const float* __restrict__ bIn,
        const float* __restrict__ sIn, const float* __restrict__ qIn,
        void* Out, float* __restrict__ ssum, float* __restrict__ ssq,
        int nRows) {
    __shared__ u16 Wl[16384];          // 32 KB swizzled W
    __shared__ u16 At[128 * 136];      // 34.8 KB bf16 A-tile, pitch 136
    __shared__ float affS[256];        // 1 KB
    float* RedS = (float*)At;          // alias At after MFMA loop
    float* RedQ = RedS + 512;
    const int t = threadIdx.x;
    const int row0 = blockIdx.x * 128;

    if (AFF) {
        if (t < 128) {
            float inv = 1.0f / (float)NN;
            float mu = sIn[t] * inv;
            float var = fmaxf(qIn[t] * inv - mu * mu, 0.f);
            float a = gIn[t] * rsqrtf(var + BN_EPS);
            affS[t] = a;
            affS[128 + t] = bIn[t] - a * mu;
        }
        __syncthreads();
    }

    // stage swizzled W: 2048 uint4
    {
        const uint4* s = (const uint4*)Wsw;
        uint4* d = (uint4*)Wl;
        #pragma unroll
        for (int i = 0; i < 8; i++) d[t + i * 256] = s[t + i * 256];
    }
    // stage A-tile (128 rows)
    if (IN16) {
        for (int i = t; i < 2048; i += 256) {
            int r  = i >> 4;
            int c8 = (i & 15) * 8;
            int gr = row0 + r;
            uint4 v = make_uint4(0u, 0u, 0u, 0u);
            if (gr < nRows) v = *(const uint4*)&((const u16*)In)[(size_t)gr * DD + c8];
            *(uint4*)&At[r * 136 + c8] = v;
        }
    } else {
        for (int i = t; i < 4096; i += 256) {
            int r  = i >> 5;
            int c4 = (i & 31) * 4;
            int gr = row0 + r;
            float4 v = make_float4(0.f, 0.f, 0.f, 0.f);
            if (gr < nRows) {
                v = *(const float4*)&((const float*)In)[(size_t)gr * DD + c4];
                if (AFF) {
                    v.x = fmaxf(fmaf(affS[c4 + 0], v.x, affS[128 + c4 + 0]), 0.f);
                    v.y = fmaxf(fmaf(affS[c4 + 1], v.y, affS[128 + c4 + 1]), 0.f);
                    v.z = fmaxf(fmaf(affS[c4 + 2], v.z, affS[128 + c4 + 2]), 0.f);
                    v.w = fmaxf(fmaf(affS[c4 + 3], v.w, affS[128 + c4 + 3]), 0.f);
                }
            }
            ushort4 o;
            o.x = f2bf(v.x); o.y = f2bf(v.y); o.z = f2bf(v.z); o.w = f2bf(v.w);
            *(ushort4*)&At[r * 136 + c4] = o;
        }
    }
    __syncthreads();

    const int w    = t >> 6;
    const int ln   = t & 63;
    const int quad = ln >> 4;
    const int lq   = ln & 15;

    f32x4 acc0[8], acc1[8];
    #pragma unroll
    for (int nt = 0; nt < 8; nt++) {
        acc0[nt] = (f32x4){0.f, 0.f, 0.f, 0.f};
        acc1[nt] = (f32x4){0.f, 0.f, 0.f, 0.f};
    }

    const u16* aRow0 = &At[(w * 32 + lq) * 136 + quad * 8];
    const u16* aRow1 = &At[(w * 32 + 16 + lq) * 136 + quad * 8];
    #pragma unroll
    for (int ks = 0; ks < 4; ks++) {
        bf16x8 a0 = *(const bf16x8*)&aRow0[ks * 32];
        bf16x8 a1 = *(const bf16x8*)&aRow1[ks * 32];
        #pragma unroll
        for (int nt = 0; nt < 8; nt++) {
            bf16x8 b = *(const bf16x8*)&Wl[((nt * 4 + ks) * 64 + ln) * 8];
            acc0[nt] = __builtin_amdgcn_mfma_f32_16x16x32_bf16(a0, b, acc0[nt], 0, 0, 0);
            acc1[nt] = __builtin_amdgcn_mfma_f32_16x16x32_bf16(a1, b, acc1[nt], 0, 0, 0);
        }
    }
    __syncthreads();   // At dead; RedS/RedQ alias it

    // epilogue: D[row=quad*4+r][col=nt*16+lq] for both M-tiles
    const int rb0 = row0 + w * 32 + quad * 4;
    const int rb1 = rb0 + 16;
    #pragma unroll
    for (int nt = 0; nt < 8; nt++) {
        int col = nt * 16 + lq;
        float bv = bias[col];
        float s = 0.f, q = 0.f;
        #pragma unroll
        for (int r = 0; r < 4; r++) {
            int gr = rb0 + r;
            if (gr < nRows) {
                float val = acc0[nt][r] + bv;
                size_t o = (size_t)gr * DD + col;
                if (OUT16) ((u16*)Out)[o] = f2bf(val);
                else       ((float*)Out)[o] = val;
                s += val; q += val * val;
            }
        }
        #pragma unroll
        for (int r = 0; r < 4; r++) {
            int gr = rb1 + r;
            if (gr < nRows) {
                float val = acc1[nt][r] + bv;
                size_t o = (size_t)gr * DD + col;
                if (OUT16) ((u16*)Out)[o] = f2bf(val);
                else       ((float*)Out)[o] = val;
                s += val; q += val * val;
            }
        }
        s += __shfl_xor(s, 16); q += __shfl_xor(q, 16);
        s += __shfl_xor(s, 32); q += __shfl_xor(q, 32);
        if (quad == 0) { RedS[w * 128 + col] = s; RedQ[w * 128 + col] = q; }
    }
    __syncthreads();
    if (t < 128) {
        float s = RedS[t] + RedS[128 + t] + RedS[256 + t] + RedS[384 + t];
        float q = RedQ[t] + RedQ[128 + t] + RedQ[256 + t] + RedQ[384 + t];
        atomicAdd(&ssum[t], s);
        atomicAdd(&ssq[t], q);
    }
}

// final h = relu(a*z2+b) -> A (fp32) + pool partials; last block divides.
// Vectorized: 2 cols/lane (u32 bf16x2 loads, float2 stores), 4-way row
// interleave -> 16 serial iters/thread (was scalar u16 loads, 32 iters).
__global__ __launch_bounds__(256, 4) void k_upool(
        const u16* __restrict__ Bz,
        const float* __restrict__ gIn, const float* __restrict__ bIn,
        const float* __restrict__ sIn, const float* __restrict__ qIn,
        const int* __restrict__ batch, float* __restrict__ A,
        float* __restrict__ gsum, const int* __restrict__ goff,
        float* __restrict__ outw, int* __restrict__ sem) {
    const int t = threadIdx.x;
    const int c = (t & 63) * 2;        // 2 cols per lane
    const int qv = t >> 6;             // rows qv + 4i (wave-uniform row)
    const int r0 = blockIdx.x * 64;
    float inv = 1.0f / (float)NN;
    float mu0 = sIn[c] * inv, mu1 = sIn[c + 1] * inv;
    float v0 = fmaxf(qIn[c] * inv - mu0 * mu0, 0.f);
    float v1 = fmaxf(qIn[c + 1] * inv - mu1 * mu1, 0.f);
    float a0 = gIn[c] * rsqrtf(v0 + BN_EPS);
    float a1 = gIn[c + 1] * rsqrtf(v1 + BN_EPS);
    float b0 = bIn[c] - a0 * mu0;
    float b1 = bIn[c + 1] - a1 * mu1;
    float acc0 = 0.f, acc1 = 0.f;
    int curg = -1;
    for (int i = 0; i < 16; i++) {
        int r = r0 + qv + 4 * i;
        if (r >= NN) break;
        int gg = batch[r];
        if (gg != curg) {
            if (curg >= 0) {
                atomicAdd(&gsum[(size_t)curg * DD + c], acc0);
                atomicAdd(&gsum[(size_t)curg * DD + c + 1], acc1);
            }
            acc0 = 0.f; acc1 = 0.f; curg = gg;
        }
        u32 wd = *(const u32*)&Bz[(size_t)r * DD + c];
        float x0 = fmaxf(fmaf(a0, bf2f((u16)(wd & 0xFFFF)), b0), 0.f);
        float x1 = fmaxf(fmaf(a1, bf2f((u16)(wd >> 16)), b1), 0.f);
        *(float2*)&A[(size_t)r * DD + c] = make_float2(x0, x1);
        acc0 += x0; acc1 += x1;
    }
    if (curg >= 0) {
        atomicAdd(&gsum[(size_t)curg * DD + c], acc0);
        atomicAdd(&gsum[(size_t)curg * DD + c + 1], acc1);
    }

    __shared__ int lastF;
    if (t == 0) {
        __threadfence();
        lastF = (atomicAdd(&sem[1], 1) == gridDim.x - 1);
    }
    __syncthreads();
    if (!lastF) return;
    __threadfence();
    for (int i = t; i < NG * DD; i += 256) {
        int g = i >> 7;
        float cnt = fmaxf((float)(goff[g + 1] - goff[g]), 1.0f);
        outw[i] = atomicAdd(&gsum[i], 0.0f) / cnt;
    }
}

extern "C" void kernel_launch(void* const* d_in, const int* in_sizes, int n_in,
                              void* d_out, int out_size, void* d_ws, size_t ws_size,
                              hipStream_t stream) {
    const int* feat  = (const int*)d_in[0];
    const int* ei    = (const int*)d_in[1];
    const int* batch = (const int*)d_in[2];
    const void* vw   = d_in[3];
    const void* vb   = d_in[4];
    const void* demb = d_in[5];
    const void* w1   = d_in[6];
    const void* b1   = d_in[7];
    const void* g1   = d_in[8];
    const void* be1  = d_in[9];
    const void* w2   = d_in[10];
    const void* b2   = d_in[11];
    const void* g2   = d_in[12];
    const void* be2  = d_in[13];

    const int* src = ei;
    const int* dst = ei + NE;
    const size_t ND = (size_t)NN * DD;

    // ---- workspace layout ----
    float* pc     = (float*)d_ws;            // 3072: b1,b2,g1,be1,g2,be2
    int*   flag   = (int*)(pc + 3072);       // 64
    float* stats  = (float*)(flag + 64);     // 2048 [zero from here...]
    float* gsum   = stats + 2048;            // 8192
    int*   deg    = (int*)(gsum + 8192);     // NN
    int*   cursor = deg + NN;                // NN
    int*   sem    = cursor + NN;             // 64  [...to here]
    int*   bsum   = sem + 64;                // 256
    int*   goff   = bsum + 256;              // 128 (65 used)
    int*   rowptr = goff + 128;              // NN+64
    int*   colidx = rowptr + NN + 64;        // NE
    u16*   Wsw    = (u16*)(colidx + NE);     // 8*16384 u16
    u16*   B      = Wsw + 8 * 16384;         // ND bf16
    u16*   Agg16  = B + ND;                  // ND bf16

    float* b1c  = pc;
    float* b2c  = pc + 512;
    float* g1c  = pc + 1024;
    float* be1c = pc + 1536;
    float* g2c  = pc + 2048;
    float* be2c = pc + 2560;
    float* sum1 = stats;          // [NL][128]
    float* sq1  = stats + 512;
    float* sum2 = stats + 1024;
    float* sq2  = stats + 1536;

    float* outw = (float*)d_out;             // [0, NG*DD): graph_feature
    float* A    = outw + (size_t)NG * DD;    // h region: fp32 z1 scratch, final h

    const int zwords = 2048 + 8192 + NN + NN + 64;  // stats, gsum, deg, cursor, sem
    const int gridND = (int)(ND / 256);             // 25000 exact
    const int gemmBlocks = (NN + 127) / 128;        // 391
    const int aggrBlocks = (NN + 3) / 4;            // 12500

    k_pre<<<2 + (zwords + 255) / 256, 256, 0, stream>>>(vb, flag, batch, goff,
                                                        stats, zwords);
    k_cvtswz<<<12 + 512, 256, 0, stream>>>(b1, b2, g1, be1, g2, be2, w1, w2,
                                           pc, Wsw, flag);
    k_deg<<<(NE + 255) / 256, 256, 0, stream>>>(dst, deg);
    k_scan12<<<NB, 256, 0, stream>>>(deg, bsum, sem);
    k_scan3init<<<NB + gridND, 256, 0, stream>>>(deg, bsum, rowptr,
                                                 feat, vw, vb, demb, B, flag);
    k_fill<<<(NE + 255) / 256, 256, 0, stream>>>(src, dst, rowptr, cursor, colidx);

    for (int l = 0; l < NL; l++) {
        const u16* W1l = Wsw + (size_t)l * 16384;
        const u16* W2l = Wsw + (size_t)(4 + l) * 16384;
        if (l == 0) {
            k_aggr<false><<<aggrBlocks, 256, 0, stream>>>(
                B, rowptr, colidx, nullptr, nullptr, nullptr, nullptr, Agg16);
        } else {
            k_aggr<true><<<aggrBlocks, 256, 0, stream>>>(
                B, rowptr, colidx, g2c + (l - 1) * 128, be2c + (l - 1) * 128,
                sum2 + (l - 1) * 128, sq2 + (l - 1) * 128, Agg16);
        }
        // GEMM1: Agg16 (bf16) -> A (fp32 z1)
        k_gemm<true, false, false><<<gemmBlocks, 256, 0, stream>>>(
            Agg16, W1l, b1c + l * 128, nullptr, nullptr, nullptr, nullptr,
            A, sum1 + l * 128, sq1 + l * 128, NN);
        // GEMM2: A (fp32 z1) -> B (bf16 z2), affine from BN1 stats
        k_gemm<false, true, true><<<gemmBlocks, 256, 0, stream>>>(
            A, W2l, b2c + l * 128, g1c + l * 128, be1c + l * 128,
            sum1 + l * 128, sq1 + l * 128,
            B, sum2 + l * 128, sq2 + l * 128, NN);
    }
    k_upool<<<(NN + 63) / 64, 256, 0, stream>>>(
        B, g2c + 3 * 128, be2c + 3 * 128, sum2 + 3 * 128, sq2 + 3 * 128,
        batch, A, gsum, goff, outw, sem);
}

// Round 4
// 548.352 us; speedup vs baseline: 1.4158x; 1.0167x over previous
//
#include <hip/hip_runtime.h>

#define NN 50000
#define NE 500000
#define DD 128
#define NL 4
#define NG 64
#define FIXED_DIM 10000
#define BN_EPS 1e-5f
#define NB 196   // ceil(NN/256)

typedef unsigned short u16;
typedef unsigned int u32;
typedef __attribute__((ext_vector_type(8))) short bf16x8;
typedef __attribute__((ext_vector_type(4))) float f32x4;

__device__ __forceinline__ float bf2f(u16 u) {
    return __uint_as_float(((u32)u) << 16);
}
__device__ __forceinline__ u16 f2bf(float f) {
    u32 u = __float_as_uint(f);
    return (u16)((u + 0x7FFFu + ((u >> 16) & 1u)) >> 16);
}
// adaptive float-INPUT load (isbf: bf16 vs fp32)
__device__ __forceinline__ float ldf(const void* p, size_t i, int isbf) {
    return isbf ? bf2f(((const u16*)p)[i]) : ((const float*)p)[i];
}

// fused preamble: block 0 = dtype probe; block 1 = goff binary search;
// blocks 2+ = zero of [stats .. sem] region (no cross-block deps).
__global__ void k_pre(const void* __restrict__ vb, int* __restrict__ flag,
                      const int* __restrict__ batch, int* __restrict__ goff,
                      float* __restrict__ zbase, int zwords) {
    int b = blockIdx.x, t = threadIdx.x;
    if (b == 0) {
        __shared__ int ok[256];
        float v = (t < 128) ? bf2f(((const u16*)vb)[t]) : 0.f;
        ok[t] = (t < 128) ? ((fabsf(v) < 1000.f) ? 1 : 0) : 1;
        __syncthreads();
        for (int off = 128; off; off >>= 1) {
            if (t < off) ok[t] &= ok[t + off];
            __syncthreads();
        }
        if (t == 0) *flag = ok[0];
    } else if (b == 1) {
        if (t <= NG) {
            int lo = 0, hi = NN;
            while (lo < hi) {
                int mid = (lo + hi) >> 1;
                if (batch[mid] < t) lo = mid + 1; else hi = mid;
            }
            goff[t] = lo;
        }
    } else {
        int i = (b - 2) * 256 + t;
        if (i < zwords) zbase[i] = 0.f;
    }
}

// merged: blocks 0..11 convert 6 per-layer param tensors (6*NL*DD = 3072)
// to fp32; blocks 12.. pre-swizzle 8 weight matrices into MFMA B-frag order:
// Wsw[m*16384 + ((nt*4+ks)*64 + lane)*8 + j]
//   = W_m[ks*32 + (lane>>4)*8 + j][nt*16 + (lane&15)]   (bf16)
__global__ void k_cvtswz(const void* b1, const void* b2, const void* g1,
                         const void* be1, const void* g2, const void* be2,
                         const void* __restrict__ w1, const void* __restrict__ w2,
                         float* __restrict__ pc, u16* __restrict__ Wsw,
                         const int* __restrict__ flag) {
    int b = blockIdx.x, tt = threadIdx.x;
    if (b < 12) {
        int t = b * 256 + tt;            // < 3072 exactly
        int p = t >> 9, j = t & 511;
        const void* s = (p == 0) ? b1 : (p == 1) ? b2 : (p == 2) ? g1
                      : (p == 3) ? be1 : (p == 4) ? g2 : be2;
        pc[t] = ldf(s, j, *flag);
    } else {
        int t = (b - 12) * 256 + tt;     // < 131072 exactly
        int m    = t >> 14;
        int idx  = t & 16383;
        int nt   = idx >> 11;
        int ks   = (idx >> 9) & 3;
        int lane = (idx >> 3) & 63;
        int j    = idx & 7;
        int row = ks * 32 + (lane >> 4) * 8 + j;
        int col = nt * 16 + (lane & 15);
        const void* src = (m < 4) ? w1 : w2;
        size_t off = (size_t)(m & 3) * DD * DD + (size_t)row * DD + col;
        Wsw[t] = f2bf(ldf(src, off, *flag));
    }
}

__global__ void k_deg(const int* __restrict__ dst, int* __restrict__ deg) {
    int i = blockIdx.x * 256 + threadIdx.x;
    if (i < NE) atomicAdd(&deg[dst[i]], 1);
}

// scan stage 1 + (last-block) stage 2: per-block sums -> exclusive scan of bsum.
// Device-scope atomics for cross-XCD visibility within the kernel.
__global__ void k_scan12(const int* __restrict__ deg, int* __restrict__ bsum,
                         int* __restrict__ sem) {
    __shared__ int S[256];
    __shared__ int lastB;
    int b = blockIdx.x, t = threadIdx.x;
    int i = b * 256 + t;
    S[t] = (i < NN) ? deg[i] : 0;
    __syncthreads();
    for (int off = 128; off; off >>= 1) {
        if (t < off) S[t] += S[t + off];
        __syncthreads();
    }
    if (t == 0) {
        atomicExch(&bsum[b], S[0]);
        __threadfence();
        lastB = (atomicAdd(&sem[0], 1) == gridDim.x - 1);
    }
    __syncthreads();
    if (!lastB) return;
    __threadfence();
    int v = (t < NB) ? atomicAdd(&bsum[t], 0) : 0;
    S[t] = v;
    __syncthreads();
    for (int off = 1; off < 256; off <<= 1) {
        int x = (t >= off) ? S[t - off] : 0;
        __syncthreads();
        S[t] += x;
        __syncthreads();
    }
    if (t < NB) bsum[t] = S[t] - v;                 // exclusive
}

// merged: blocks 0..NB-1 finish the rowptr scan; blocks NB.. compute
// h0 = vw[feat] + vb + deg_emb[min(deg,1000)] -> B (bf16).
__global__ void k_scan3init(const int* __restrict__ deg, const int* __restrict__ bsum,
                            int* __restrict__ rowptr,
                            const int* __restrict__ feat, const void* __restrict__ vw,
                            const void* __restrict__ vb, const void* __restrict__ demb,
                            u16* __restrict__ B, const int* __restrict__ flag) {
    __shared__ int S[256];
    int b = blockIdx.x, t = threadIdx.x;
    if (b < NB) {
        int i = b * 256 + t;
        int v = (i < NN) ? deg[i] : 0;
        S[t] = v;
        __syncthreads();
        for (int off = 1; off < 256; off <<= 1) {
            int x = (t >= off) ? S[t - off] : 0;
            __syncthreads();
            S[t] += x;
            __syncthreads();
        }
        if (i < NN) rowptr[i] = bsum[b] + S[t] - v;
        if (i == NN - 1) rowptr[NN] = bsum[b] + S[t];   // == NE
    } else {
        int idx = (b - NB) * 256 + t;
        if (idx >= NN * DD) return;
        int n = idx >> 7, c = idx & 127;
        int isbf = *flag;
        int f = feat[n] % FIXED_DIM;
        int dg = min(deg[n], 1000);
        B[idx] = f2bf(ldf(vw, (size_t)f * DD + c, isbf)
                    + ldf(vb, c, isbf)
                    + ldf(demb, (size_t)dg * DD + c, isbf));
    }
}

__global__ void k_fill(const int* __restrict__ src, const int* __restrict__ dst,
                       const int* __restrict__ rowptr, int* __restrict__ cursor,
                       int* __restrict__ colidx) {
    int e = blockIdx.x * 256 + threadIdx.x;
    if (e >= NE) return;
    int d = dst[e];
    int p = atomicAdd(&cursor[d], 1);
    colidx[rowptr[d] + p] = src[e];
}

// GIN aggregation with fused h-recompute, bf16 out (proven structure:
// 1 row/wave, 2 cols/lane, occupancy 8 -> max TLP for the latency-bound gather).
//   f(x) = AFF ? relu(a[c]*x + b[c]) : x   (a,b from prev layer's BN2 stats)
//   Agg[n] = f(B[n]) + sum_{j in row n} f(B[colidx[j]])
template <bool AFF>
__global__ __launch_bounds__(256, 8) void k_aggr(
        const u16* __restrict__ B, const int* __restrict__ rowptr,
        const int* __restrict__ colidx,
        const float* __restrict__ gIn, const float* __restrict__ bIn,
        const float* __restrict__ sIn, const float* __restrict__ qIn,
        u16* __restrict__ Agg) {
    int n = blockIdx.x * 4 + (threadIdx.x >> 6);
    if (n >= NN) return;
    int c = (threadIdx.x & 63) * 2;
    float a0 = 1.f, b0 = 0.f, a1 = 1.f, b1 = 0.f;
    if (AFF) {
        float inv = 1.0f / (float)NN;
        float mu0 = sIn[c] * inv, mu1 = sIn[c + 1] * inv;
        float v0 = fmaxf(qIn[c] * inv - mu0 * mu0, 0.f);
        float v1 = fmaxf(qIn[c + 1] * inv - mu1 * mu1, 0.f);
        a0 = gIn[c] * rsqrtf(v0 + BN_EPS);
        a1 = gIn[c + 1] * rsqrtf(v1 + BN_EPS);
        b0 = bIn[c] - a0 * mu0;
        b1 = bIn[c + 1] - a1 * mu1;
    }
    u32 w = *(const u32*)&B[(size_t)n * DD + c];
    float x0 = bf2f((u16)(w & 0xFFFF)), x1 = bf2f((u16)(w >> 16));
    float s0 = AFF ? fmaxf(fmaf(a0, x0, b0), 0.f) : x0;
    float s1 = AFF ? fmaxf(fmaf(a1, x1, b1), 0.f) : x1;
    int lo = rowptr[n], hi = rowptr[n + 1];
    int j = lo;
    for (; j + 4 <= hi; j += 4) {
        int m0 = colidx[j], m1 = colidx[j + 1];
        int m2 = colidx[j + 2], m3 = colidx[j + 3];
        u32 w0 = *(const u32*)&B[(size_t)m0 * DD + c];
        u32 w1v = *(const u32*)&B[(size_t)m1 * DD + c];
        u32 w2v = *(const u32*)&B[(size_t)m2 * DD + c];
        u32 w3v = *(const u32*)&B[(size_t)m3 * DD + c];
        float y;
        y = bf2f((u16)(w0 & 0xFFFF)); s0 += AFF ? fmaxf(fmaf(a0, y, b0), 0.f) : y;
        y = bf2f((u16)(w0 >> 16));    s1 += AFF ? fmaxf(fmaf(a1, y, b1), 0.f) : y;
        y = bf2f((u16)(w1v & 0xFFFF)); s0 += AFF ? fmaxf(fmaf(a0, y, b0), 0.f) : y;
        y = bf2f((u16)(w1v >> 16));    s1 += AFF ? fmaxf(fmaf(a1, y, b1), 0.f) : y;
        y = bf2f((u16)(w2v & 0xFFFF)); s0 += AFF ? fmaxf(fmaf(a0, y, b0), 0.f) : y;
        y = bf2f((u16)(w2v >> 16));    s1 += AFF ? fmaxf(fmaf(a1, y, b1), 0.f) : y;
        y = bf2f((u16)(w3v & 0xFFFF)); s0 += AFF ? fmaxf(fmaf(a0, y, b0), 0.f) : y;
        y = bf2f((u16)(w3v >> 16));    s1 += AFF ? fmaxf(fmaf(a1, y, b1), 0.f) : y;
    }
    for (; j < hi; j++) {
        int m = colidx[j];
        w = *(const u32*)&B[(size_t)m * DD + c];
        x0 = bf2f((u16)(w & 0xFFFF)); x1 = bf2f((u16)(w >> 16));
        s0 += AFF ? fmaxf(fmaf(a0, x0, b0), 0.f) : x0;
        s1 += AFF ? fmaxf(fmaf(a1, x1, b1), 0.f) : x1;
    }
    *(u32*)&Agg[(size_t)n * DD + c] = ((u32)f2bf(s1) << 16) | (u32)f2bf(s0);
}

// ---- MFMA GEMM, 128 rows x 128 cols per block (391 blocks) ----
// PROVEN config: fewer, larger blocks win for this K=128, staging/epilogue-
// dominated GEMM (64-row variant measured +14us/dispatch, round 2).
// Out = f(In) @ W + bias; f = AFF ? relu(aff*x+b) : id.
// Wave w owns rows w*32..w*32+31 (2 M-tiles); 64 MFMAs/wave.
// LDS: Wl 32K + At 34.8K + affS 1K = 68.6 KB -> 2 blocks/CU.
// Red buffers alias At (dead after MFMA loop). In-place safe (block-local rows).
template <bool IN16, bool OUT16, bool AFF>
__global__ __launch_bounds__(256, 2) void k_gemm(
        const void* In, const u16* __restrict__ Wsw,
        const float* __restrict__ bias,
        const float* __restrict__ gIn, const float* __restrict__ bIn,
        const float* __restrict__ sIn, const float* __restrict__ qIn,
        void* Out, float* __restrict__ ssum, float* __restrict__ ssq,
        int nRows) {
    __shared__ u16 Wl[16384];          // 32 KB swizzled W
    __shared__ u16 At[128 * 136];      // 34.8 KB bf16 A-tile, pitch 136
    __shared__ float affS[256];        // 1 KB
    float* RedS = (float*)At;          // alias At after MFMA loop
    float* RedQ = RedS + 512;
    const int t = threadIdx.x;
    const int row0 = blockIdx.x * 128;

    if (AFF) {
        if (t < 128) {
            float inv = 1.0f / (float)NN;
            float mu = sIn[t] * inv;
            float var = fmaxf(qIn[t] * inv - mu * mu, 0.f);
            float a = gIn[t] * rsqrtf(var + BN_EPS);
            affS[t] = a;
            affS[128 + t] = bIn[t] - a * mu;
        }
        __syncthreads();
    }

    // stage swizzled W: 2048 uint4
    {
        const uint4* s = (const uint4*)Wsw;
        uint4* d = (uint4*)Wl;
        #pragma unroll
        for (int i = 0; i < 8; i++) d[t + i * 256] = s[t + i * 256];
    }
    // stage A-tile (128 rows)
    if (IN16) {
        for (int i = t; i < 2048; i += 256) {
            int r  = i >> 4;
            int c8 = (i & 15) * 8;
            int gr = row0 + r;
            uint4 v = make_uint4(0u, 0u, 0u, 0u);
            if (gr < nRows) v = *(const uint4*)&((const u16*)In)[(size_t)gr * DD + c8];
            *(uint4*)&At[r * 136 + c8] = v;
        }
    } else {
        for (int i = t; i < 4096; i += 256) {
            int r  = i >> 5;
            int c4 = (i & 31) * 4;
            int gr = row0 + r;
            float4 v = make_float4(0.f, 0.f, 0.f, 0.f);
            if (gr < nRows) {
                v = *(const float4*)&((const float*)In)[(size_t)gr * DD + c4];
                if (AFF) {
                    v.x = fmaxf(fmaf(affS[c4 + 0], v.x, affS[128 + c4 + 0]), 0.f);
                    v.y = fmaxf(fmaf(affS[c4 + 1], v.y, affS[128 + c4 + 1]), 0.f);
                    v.z = fmaxf(fmaf(affS[c4 + 2], v.z, affS[128 + c4 + 2]), 0.f);
                    v.w = fmaxf(fmaf(affS[c4 + 3], v.w, affS[128 + c4 + 3]), 0.f);
                }
            }
            ushort4 o;
            o.x = f2bf(v.x); o.y = f2bf(v.y); o.z = f2bf(v.z); o.w = f2bf(v.w);
            *(ushort4*)&At[r * 136 + c4] = o;
        }
    }
    __syncthreads();

    const int w    = t >> 6;
    const int ln   = t & 63;
    const int quad = ln >> 4;
    const int lq   = ln & 15;

    f32x4 acc0[8], acc1[8];
    #pragma unroll
    for (int nt = 0; nt < 8; nt++) {
        acc0[nt] = (f32x4){0.f, 0.f, 0.f, 0.f};
        acc1[nt] = (f32x4){0.f, 0.f, 0.f, 0.f};
    }

    const u16* aRow0 = &At[(w * 32 + lq) * 136 + quad * 8];
    const u16* aRow1 = &At[(w * 32 + 16 + lq) * 136 + quad * 8];
    #pragma unroll
    for (int ks = 0; ks < 4; ks++) {
        bf16x8 a0 = *(const bf16x8*)&aRow0[ks * 32];
        bf16x8 a1 = *(const bf16x8*)&aRow1[ks * 32];
        #pragma unroll
        for (int nt = 0; nt < 8; nt++) {
            bf16x8 b = *(const bf16x8*)&Wl[((nt * 4 + ks) * 64 + ln) * 8];
            acc0[nt] = __builtin_amdgcn_mfma_f32_16x16x32_bf16(a0, b, acc0[nt], 0, 0, 0);
            acc1[nt] = __builtin_amdgcn_mfma_f32_16x16x32_bf16(a1, b, acc1[nt], 0, 0, 0);
        }
    }
    __syncthreads();   // At dead; RedS/RedQ alias it

    // epilogue: D[row=quad*4+r][col=nt*16+lq] for both M-tiles
    const int rb0 = row0 + w * 32 + quad * 4;
    const int rb1 = rb0 + 16;
    #pragma unroll
    for (int nt = 0; nt < 8; nt++) {
        int col = nt * 16 + lq;
        float bv = bias[col];
        float s = 0.f, q = 0.f;
        #pragma unroll
        for (int r = 0; r < 4; r++) {
            int gr = rb0 + r;
            if (gr < nRows) {
                float val = acc0[nt][r] + bv;
                size_t o = (size_t)gr * DD + col;
                if (OUT16) ((u16*)Out)[o] = f2bf(val);
                else       ((float*)Out)[o] = val;
                s += val; q += val * val;
            }
        }
        #pragma unroll
        for (int r = 0; r < 4; r++) {
            int gr = rb1 + r;
            if (gr < nRows) {
                float val = acc1[nt][r] + bv;
                size_t o = (size_t)gr * DD + col;
                if (OUT16) ((u16*)Out)[o] = f2bf(val);
                else       ((float*)Out)[o] = val;
                s += val; q += val * val;
            }
        }
        s += __shfl_xor(s, 16); q += __shfl_xor(q, 16);
        s += __shfl_xor(s, 32); q += __shfl_xor(q, 32);
        if (quad == 0) { RedS[w * 128 + col] = s; RedQ[w * 128 + col] = q; }
    }
    __syncthreads();
    if (t < 128) {
        float s = RedS[t] + RedS[128 + t] + RedS[256 + t] + RedS[384 + t];
        float q = RedQ[t] + RedQ[128 + t] + RedQ[256 + t] + RedQ[384 + t];
        atomicAdd(&ssum[t], s);
        atomicAdd(&ssq[t], q);
    }
}

// final h = relu(a*z2+b) -> A (fp32) + pool partials; last block divides.
// Hierarchical pool reduction: batch is sorted and every graph has >=781
// rows, so a 64-row block spans at most 2 graphs (g_lo, g_hi). Each thread
// accumulates 2 register buckets (no loop-carried branch -> loads pipeline),
// then a 4-wave LDS reduction collapses to 1 atomic per column per
// block-graph (~108K total vs ~480K) — same-address atomic chains were the
// measured 52us floor (invariant to load width, rounds 2-3).
__global__ __launch_bounds__(256, 4) void k_upool(
        const u16* __restrict__ Bz,
        const float* __restrict__ gIn, const float* __restrict__ bIn,
        const float* __restrict__ sIn, const float* __restrict__ qIn,
        const int* __restrict__ batch, float* __restrict__ A,
        float* __restrict__ gsum, const int* __restrict__ goff,
        float* __restrict__ outw, int* __restrict__ sem) {
    const int t = threadIdx.x;
    const int c = (t & 63) * 2;        // 2 cols per lane
    const int qv = t >> 6;             // rows qv + 4i (wave-uniform row)
    const int r0 = blockIdx.x * 64;
    const int g_lo = batch[r0];
    const int g_hi = batch[min(r0 + 63, NN - 1)];
    float inv = 1.0f / (float)NN;
    float mu0 = sIn[c] * inv, mu1 = sIn[c + 1] * inv;
    float v0 = fmaxf(qIn[c] * inv - mu0 * mu0, 0.f);
    float v1 = fmaxf(qIn[c + 1] * inv - mu1 * mu1, 0.f);
    float a0 = gIn[c] * rsqrtf(v0 + BN_EPS);
    float a1 = gIn[c + 1] * rsqrtf(v1 + BN_EPS);
    float b0 = bIn[c] - a0 * mu0;
    float b1 = bIn[c + 1] - a1 * mu1;
    float lo0 = 0.f, lo1 = 0.f, hi0 = 0.f, hi1 = 0.f;
    #pragma unroll
    for (int i = 0; i < 16; i++) {
        int r = r0 + qv + 4 * i;
        if (r >= NN) break;
        u32 wd = *(const u32*)&Bz[(size_t)r * DD + c];
        float x0 = fmaxf(fmaf(a0, bf2f((u16)(wd & 0xFFFF)), b0), 0.f);
        float x1 = fmaxf(fmaf(a1, bf2f((u16)(wd >> 16)), b1), 0.f);
        *(float2*)&A[(size_t)r * DD + c] = make_float2(x0, x1);
        if (batch[r] == g_lo) { lo0 += x0; lo1 += x1; }
        else                  { hi0 += x0; hi1 += x1; }
    }
    __shared__ float2 PL[4][64];
    __shared__ float2 PH[4][64];
    PL[qv][t & 63] = make_float2(lo0, lo1);
    PH[qv][t & 63] = make_float2(hi0, hi1);
    __syncthreads();
    if (t < 64) {
        float2 p0 = PL[0][t], p1 = PL[1][t], p2 = PL[2][t], p3 = PL[3][t];
        atomicAdd(&gsum[(size_t)g_lo * DD + 2 * t],     p0.x + p1.x + p2.x + p3.x);
        atomicAdd(&gsum[(size_t)g_lo * DD + 2 * t + 1], p0.y + p1.y + p2.y + p3.y);
    } else if (t < 128 && g_hi != g_lo) {
        int u = t - 64;
        float2 p0 = PH[0][u], p1 = PH[1][u], p2 = PH[2][u], p3 = PH[3][u];
        atomicAdd(&gsum[(size_t)g_hi * DD + 2 * u],     p0.x + p1.x + p2.x + p3.x);
        atomicAdd(&gsum[(size_t)g_hi * DD + 2 * u + 1], p0.y + p1.y + p2.y + p3.y);
    }

    __shared__ int lastF;
    if (t == 0) {
        __threadfence();
        lastF = (atomicAdd(&sem[1], 1) == gridDim.x - 1);
    }
    __syncthreads();
    if (!lastF) return;
    __threadfence();
    for (int i = t; i < NG * DD; i += 256) {
        int g = i >> 7;
        float cnt = fmaxf((float)(goff[g + 1] - goff[g]), 1.0f);
        outw[i] = atomicAdd(&gsum[i], 0.0f) / cnt;
    }
}

extern "C" void kernel_launch(void* const* d_in, const int* in_sizes, int n_in,
                              void* d_out, int out_size, void* d_ws, size_t ws_size,
                              hipStream_t stream) {
    const int* feat  = (const int*)d_in[0];
    const int* ei    = (const int*)d_in[1];
    const int* batch = (const int*)d_in[2];
    const void* vw   = d_in[3];
    const void* vb   = d_in[4];
    const void* demb = d_in[5];
    const void* w1   = d_in[6];
    const void* b1   = d_in[7];
    const void* g1   = d_in[8];
    const void* be1  = d_in[9];
    const void* w2   = d_in[10];
    const void* b2   = d_in[11];
    const void* g2   = d_in[12];
    const void* be2  = d_in[13];

    const int* src = ei;
    const int* dst = ei + NE;
    const size_t ND = (size_t)NN * DD;

    // ---- workspace layout ----
    float* pc     = (float*)d_ws;            // 3072: b1,b2,g1,be1,g2,be2
    int*   flag   = (int*)(pc + 3072);       // 64
    float* stats  = (float*)(flag + 64);     // 2048 [zero from here...]
    float* gsum   = stats + 2048;            // 8192
    int*   deg    = (int*)(gsum + 8192);     // NN
    int*   cursor = deg + NN;                // NN
    int*   sem    = cursor + NN;             // 64  [...to here]
    int*   bsum   = sem + 64;                // 256
    int*   goff   = bsum + 256;              // 128 (65 used)
    int*   rowptr = goff + 128;              // NN+64
    int*   colidx = rowptr + NN + 64;        // NE
    u16*   Wsw    = (u16*)(colidx + NE);     // 8*16384 u16
    u16*   B      = Wsw + 8 * 16384;         // ND bf16
    u16*   Agg16  = B + ND;                  // ND bf16

    float* b1c  = pc;
    float* b2c  = pc + 512;
    float* g1c  = pc + 1024;
    float* be1c = pc + 1536;
    float* g2c  = pc + 2048;
    float* be2c = pc + 2560;
    float* sum1 = stats;          // [NL][128]
    float* sq1  = stats + 512;
    float* sum2 = stats + 1024;
    float* sq2  = stats + 1536;

    float* outw = (float*)d_out;             // [0, NG*DD): graph_feature
    float* A    = outw + (size_t)NG * DD;    // h region: fp32 z1 scratch, final h

    const int zwords = 2048 + 8192 + NN + NN + 64;  // stats, gsum, deg, cursor, sem
    const int gridND = (int)(ND / 256);             // 25000 exact
    const int gemmBlocks = (NN + 127) / 128;        // 391
    const int aggrBlocks = (NN + 3) / 4;            // 12500

    k_pre<<<2 + (zwords + 255) / 256, 256, 0, stream>>>(vb, flag, batch, goff,
                                                        stats, zwords);
    k_cvtswz<<<12 + 512, 256, 0, stream>>>(b1, b2, g1, be1, g2, be2, w1, w2,
                                           pc, Wsw, flag);
    k_deg<<<(NE + 255) / 256, 256, 0, stream>>>(dst, deg);
    k_scan12<<<NB, 256, 0, stream>>>(deg, bsum, sem);
    k_scan3init<<<NB + gridND, 256, 0, stream>>>(deg, bsum, rowptr,
                                                 feat, vw, vb, demb, B, flag);
    k_fill<<<(NE + 255) / 256, 256, 0, stream>>>(src, dst, rowptr, cursor, colidx);

    for (int l = 0; l < NL; l++) {
        const u16* W1l = Wsw + (size_t)l * 16384;
        const u16* W2l = Wsw + (size_t)(4 + l) * 16384;
        if (l == 0) {
            k_aggr<false><<<aggrBlocks, 256, 0, stream>>>(
                B, rowptr, colidx, nullptr, nullptr, nullptr, nullptr, Agg16);
        } else {
            k_aggr<true><<<aggrBlocks, 256, 0, stream>>>(
                B, rowptr, colidx, g2c + (l - 1) * 128, be2c + (l - 1) * 128,
                sum2 + (l - 1) * 128, sq2 + (l - 1) * 128, Agg16);
        }
        // GEMM1: Agg16 (bf16) -> A (fp32 z1)
        k_gemm<true, false, false><<<gemmBlocks, 256, 0, stream>>>(
            Agg16, W1l, b1c + l * 128, nullptr, nullptr, nullptr, nullptr,
            A, sum1 + l * 128, sq1 + l * 128, NN);
        // GEMM2: A (fp32 z1) -> B (bf16 z2), affine from BN1 stats
        k_gemm<false, true, true><<<gemmBlocks, 256, 0, stream>>>(
            A, W2l, b2c + l * 128, g1c + l * 128, be1c + l * 128,
            sum1 + l * 128, sq1 + l * 128,
            B, sum2 + l * 128, sq2 + l * 128, NN);
    }
    k_upool<<<(NN + 63) / 64, 256, 0, stream>>>(
        B, g2c + 3 * 128, be2c + 3 * 128, sum2 + 3 * 128, sq2 + 3 * 128,
        batch, A, gsum, goff, outw, sem);
}